// Round 1
// baseline (1604.149 us; speedup 1.0000x reference)
//
#include <hip/hip_runtime.h>

#define B_   256
#define NIN_ 512
#define T_   256
#define H1_  512
#define H2_  512
#define OUT_ 128

// ---------------------------------------------------------------------------
// Per-tensor absmax -> scale = max|W|/127.  One block per tensor.
// ---------------------------------------------------------------------------
__global__ void absmax_k(const float* __restrict__ W1, const float* __restrict__ W2,
                         const float* __restrict__ Wr, const float* __restrict__ W3,
                         float* __restrict__ scales) {
  const float* W; int n;
  switch (blockIdx.x) {
    case 0:  W = W1; n = H1_ * NIN_; break;
    case 1:  W = W2; n = H2_ * H1_;  break;
    case 2:  W = Wr; n = H2_ * H2_;  break;
    default: W = W3; n = OUT_ * H2_; break;
  }
  int tid = threadIdx.x;
  float m = 0.f;
  const float4* W4 = (const float4*)W;
  int n4 = n >> 2;
  for (int i = tid; i < n4; i += 256) {
    float4 v = W4[i];
    m = fmaxf(m, fmaxf(fmaxf(fabsf(v.x), fabsf(v.y)), fmaxf(fabsf(v.z), fabsf(v.w))));
  }
  __shared__ float red[256];
  red[tid] = m;
  __syncthreads();
  for (int s = 128; s > 0; s >>= 1) {
    if (tid < s) red[tid] = fmaxf(red[tid], red[tid + s]);
    __syncthreads();
  }
  if (tid == 0) scales[blockIdx.x] = red[0] / 127.0f;
}

// ---------------------------------------------------------------------------
// W1 fake-quant to fp32 values q*s (for the dense fp32 GEMM).
// ---------------------------------------------------------------------------
__global__ void quant_w1_k(const float* __restrict__ W1, const float* __restrict__ scales,
                           float* __restrict__ W1q) {
  int idx = blockIdx.x * 256 + threadIdx.x;   // grid covers exactly H1_*NIN_
  float s = scales[0];
  float q = rintf(W1[idx] / s);
  q = fminf(fmaxf(q, -127.f), 127.f);
  W1q[idx] = q * s;
}

// ---------------------------------------------------------------------------
// Quantize to int8 and TRANSPOSE: W[r][c] (r = out-dim) -> WT[c*rows + r].
// Gather layout: row c of WT is the weight column feeding from presyn unit c.
// ---------------------------------------------------------------------------
__global__ void quant_t_k(const float* __restrict__ W, const float* __restrict__ scales, int si,
                          signed char* __restrict__ WT, int rows, int cols) {
  int idx = blockIdx.x * 256 + threadIdx.x;
  if (idx >= rows * cols) return;
  int r = idx / cols;
  int c = idx - r * cols;
  float s = scales[si];
  float q = rintf(W[idx] / s);
  q = fminf(fmaxf(q, -127.f), 127.f);
  WT[(size_t)c * rows + r] = (signed char)q;
}

// ---------------------------------------------------------------------------
// Phase A: cur1[t,b,h] = sum_i data[b,i,t] * W1q[h,i]
// fp32 tiled GEMM, M=t (128), N=h (128), K=i (8 per iter), 256 thr, 8x8/thread.
// grid = (8, 256): blockIdx.x -> (tTile = x>>2, hTile = x&3), blockIdx.y = b.
// ---------------------------------------------------------------------------
__global__ __launch_bounds__(256) void gemm_cur1_k(const float* __restrict__ data,
                                                   const float* __restrict__ W1q,
                                                   float* __restrict__ cur1) {
  const int b  = blockIdx.y;
  const int t0 = (blockIdx.x >> 2) * 128;
  const int h0 = (blockIdx.x & 3) * 128;
  const int tid = threadIdx.x;

  __shared__ float As[8][128];   // As[k][t]
  __shared__ float Bs[8][128];   // Bs[k][h]

  const int ty = tid >> 4;       // 0..15  (t quad)
  const int tx = tid & 15;       // 0..15  (h quad)

  float acc[8][8];
#pragma unroll
  for (int i = 0; i < 8; i++)
#pragma unroll
    for (int j = 0; j < 8; j++) acc[i][j] = 0.f;

  // global->LDS load mapping
  const int ak = tid >> 5;            // 0..7  (k row of As)
  const int at = (tid & 31) << 2;     // 0..124 (t col, float4)
  const int bh = tid >> 1;            // 0..127 (h row of W1q)
  const int bk = (tid & 1) << 2;      // 0 or 4 (k col, float4)

  const float* dptr = data + (size_t)b * NIN_ * T_ + (size_t)ak * T_ + t0 + at;
  const float* wptr = W1q + (size_t)(h0 + bh) * NIN_ + bk;

  for (int kb = 0; kb < NIN_; kb += 8) {
    float4 av = *(const float4*)(dptr + (size_t)kb * T_);
    float4 wv = *(const float4*)(wptr + kb);
    __syncthreads();               // previous compute done before overwrite
    *(float4*)&As[ak][at] = av;
    Bs[bk + 0][bh] = wv.x;
    Bs[bk + 1][bh] = wv.y;
    Bs[bk + 2][bh] = wv.z;
    Bs[bk + 3][bh] = wv.w;
    __syncthreads();
#pragma unroll
    for (int k = 0; k < 8; k++) {
      float4 a0 = *(const float4*)&As[k][ty * 4];
      float4 a1 = *(const float4*)&As[k][64 + ty * 4];
      float4 b0 = *(const float4*)&Bs[k][tx * 4];
      float4 b1 = *(const float4*)&Bs[k][64 + tx * 4];
      float a[8] = {a0.x, a0.y, a0.z, a0.w, a1.x, a1.y, a1.z, a1.w};
      float w[8] = {b0.x, b0.y, b0.z, b0.w, b1.x, b1.y, b1.z, b1.w};
#pragma unroll
      for (int i = 0; i < 8; i++)
#pragma unroll
        for (int j = 0; j < 8; j++)
          acc[i][j] = fmaf(a[i], w[j], acc[i][j]);
    }
  }

  // store: cur1 layout [T, B, H1]
#pragma unroll
  for (int i = 0; i < 8; i++) {
    int row = (i < 4) ? (ty * 4 + i) : (64 + ty * 4 + (i - 4));
    float* op = cur1 + (size_t)(t0 + row) * (B_ * H1_) + (size_t)b * H1_ + h0;
    float4 c0 = {acc[i][0], acc[i][1], acc[i][2], acc[i][3]};
    float4 c1 = {acc[i][4], acc[i][5], acc[i][6], acc[i][7]};
    *(float4*)(op + tx * 4)      = c0;
    *(float4*)(op + 64 + tx * 4) = c1;
  }
}

// ---------------------------------------------------------------------------
// Phase B: the sequential SNN recurrence. One block per batch row, 512 thr.
// Spike GEMMs via active-row gather of int8 transposed weights (exact int sums).
// ---------------------------------------------------------------------------
__global__ __launch_bounds__(512) void recurrent_k(
    const float* __restrict__ cur1,        // [T, B, H1]
    const signed char* __restrict__ W2T,   // [H1][H2]  (presyn-major)
    const signed char* __restrict__ WrT,   // [H2][H2]
    const signed char* __restrict__ W3T,   // [H2][OUT]
    const float* __restrict__ scales,      // s1,s2,sr,s3
    const float* __restrict__ beta1p, const float* __restrict__ th1p,
    const float* __restrict__ betarp, const float* __restrict__ thrp,
    const float* __restrict__ beta2p, const float* __restrict__ th2p,
    float* __restrict__ out)               // [T, B, OUT]
{
  const int b = blockIdx.x;
  const int tid = threadIdx.x;

  const float s2sc = scales[1];
  const float srsc = scales[2];
  const float s3sc = scales[3];
  const float b1 = fminf(fmaxf(beta1p[0], 0.f), 1.f);
  const float br = fminf(fmaxf(betarp[0], 0.f), 1.f);
  const float b2 = fminf(fmaxf(beta2p[0], 0.f), 1.f);
  const float th1 = th1p[0], thr = thrp[0], th2 = th2p[0];

  __shared__ int list1[H1_];
  __shared__ int listr[H2_];
  __shared__ int n1s, nrs;

  float m1 = 0.f, mr = 0.f, m2 = 0.f;
  float sr_own = 0.f;   // this thread's previous-step recurrent spike (j = tid)

  if (tid == 0) { n1s = 0; nrs = 0; }
  __syncthreads();

  const float* curb = cur1 + (size_t)b * H1_;

  for (int t = 0; t < T_; t++) {
    // ---- layer 1 LIF (reset_delay=false) + build spike list ----
    float c = curb[(size_t)t * (B_ * H1_) + tid];
    m1 = b1 * m1 + c;
    if (m1 - th1 > 0.f) {
      int p = atomicAdd(&n1s, 1);
      list1[p] = tid;
      m1 = 0.f;
    }
    __syncthreads();    // list1 complete; listr (prev step) still valid
    const int n1 = n1s;
    const int nr = nrs;

    // ---- h = s1@W2q.T + sr@Wrq.T  (exact integer gather) ----
    int acc2 = 0, accr = 0;
    {
      int k = 0;
      for (; k + 3 < n1; k += 4) {
        int i0 = list1[k], i1 = list1[k + 1], i2 = list1[k + 2], i3 = list1[k + 3];
        acc2 += (int)W2T[(i0 << 9) + tid] + (int)W2T[(i1 << 9) + tid]
              + (int)W2T[(i2 << 9) + tid] + (int)W2T[(i3 << 9) + tid];
      }
      for (; k < n1; k++) acc2 += (int)W2T[(list1[k] << 9) + tid];
      k = 0;
      for (; k + 3 < nr; k += 4) {
        int i0 = listr[k], i1 = listr[k + 1], i2 = listr[k + 2], i3 = listr[k + 3];
        accr += (int)WrT[(i0 << 9) + tid] + (int)WrT[(i1 << 9) + tid]
              + (int)WrT[(i2 << 9) + tid] + (int)WrT[(i3 << 9) + tid];
      }
      for (; k < nr; k++) accr += (int)WrT[(listr[k] << 9) + tid];
    }
    float h = s2sc * (float)acc2 + srsc * (float)accr;

    // ---- recurrent LIF (reset_delay=true: previous sr resets now) ----
    mr = (br * mr + h) * (1.f - sr_own);
    sr_own = (mr - thr > 0.f) ? 1.f : 0.f;

    __syncthreads();    // all gathers done consuming old listr
    if (tid == 0) { n1s = 0; nrs = 0; }
    __syncthreads();
    if (sr_own != 0.f) {
      int p = atomicAdd(&nrs, 1);
      listr[p] = tid;
    }
    __syncthreads();    // new listr complete
    const int nr2 = nrs;

    // ---- layer 2 LIF + output spikes ----
    if (tid < OUT_) {
      int acc3 = 0;
      int k = 0;
      for (; k + 3 < nr2; k += 4) {
        int j0 = listr[k], j1 = listr[k + 1], j2 = listr[k + 2], j3 = listr[k + 3];
        acc3 += (int)W3T[(j0 << 7) + tid] + (int)W3T[(j1 << 7) + tid]
              + (int)W3T[(j2 << 7) + tid] + (int)W3T[(j3 << 7) + tid];
      }
      for (; k < nr2; k++) acc3 += (int)W3T[(listr[k] << 7) + tid];
      float cur3 = s3sc * (float)acc3;
      m2 = b2 * m2 + cur3;
      float spk = (m2 - th2 > 0.f) ? 1.f : 0.f;
      m2 *= (1.f - spk);
      out[(size_t)t * (B_ * OUT_) + (size_t)b * OUT_ + tid] = spk;
    }
  }
}

// ---------------------------------------------------------------------------
extern "C" void kernel_launch(void* const* d_in, const int* in_sizes, int n_in,
                              void* d_out, int out_size, void* d_ws, size_t ws_size,
                              hipStream_t stream) {
  const float* data  = (const float*)d_in[0];
  const float* W1    = (const float*)d_in[1];
  const float* W2    = (const float*)d_in[2];
  const float* Wr    = (const float*)d_in[3];
  const float* W3    = (const float*)d_in[4];
  const float* beta1 = (const float*)d_in[5];
  const float* th1   = (const float*)d_in[6];
  const float* betar = (const float*)d_in[7];
  const float* thr   = (const float*)d_in[8];
  const float* beta2 = (const float*)d_in[9];
  const float* th2   = (const float*)d_in[10];

  char* ws = (char*)d_ws;
  float*       scales = (float*)ws;                              // 4 floats (pad to 256B)
  float*       W1q    = (float*)(ws + 256);                      // 1 MB
  signed char* W2T    = (signed char*)(ws + 256 + 1048576);      // 256 KB
  signed char* WrT    = W2T + (size_t)H1_ * H2_;                 // 256 KB
  signed char* W3T    = WrT + (size_t)H2_ * H2_;                 // 64 KB
  float*       cur1   = (float*)(ws + 256 + 1048576
                                 + (size_t)H1_ * H2_ + (size_t)H2_ * H2_
                                 + (size_t)H2_ * OUT_);          // 128 MB [T,B,H1]

  hipLaunchKernelGGL(absmax_k, dim3(4), dim3(256), 0, stream, W1, W2, Wr, W3, scales);
  hipLaunchKernelGGL(quant_w1_k, dim3((H1_ * NIN_) / 256), dim3(256), 0, stream, W1, scales, W1q);
  hipLaunchKernelGGL(quant_t_k, dim3((H2_ * H1_) / 256), dim3(256), 0, stream, W2, scales, 1, W2T, H2_, H1_);
  hipLaunchKernelGGL(quant_t_k, dim3((H2_ * H2_) / 256), dim3(256), 0, stream, Wr, scales, 2, WrT, H2_, H2_);
  hipLaunchKernelGGL(quant_t_k, dim3((OUT_ * H2_) / 256), dim3(256), 0, stream, W3, scales, 3, W3T, OUT_, H2_);
  hipLaunchKernelGGL(gemm_cur1_k, dim3(8, 256), dim3(256), 0, stream, data, W1q, cur1);
  hipLaunchKernelGGL(recurrent_k, dim3(256), dim3(512), 0, stream, cur1, W2T, WrT, W3T, scales,
                     beta1, th1, betar, thr, beta2, th2, (float*)d_out);
}

// Round 2
// 1277.585 us; speedup vs baseline: 1.2556x; 1.2556x over previous
//
#include <hip/hip_runtime.h>

#define B_   256
#define NIN_ 512
#define T_   256
#define H1_  512
#define H2_  512
#define OUT_ 128

// ---------------------------------------------------------------------------
// Per-tensor absmax -> scale = max|W|/127.  One block per tensor.
// ---------------------------------------------------------------------------
__global__ void absmax_k(const float* __restrict__ W1, const float* __restrict__ W2,
                         const float* __restrict__ Wr, const float* __restrict__ W3,
                         float* __restrict__ scales) {
  const float* W; int n;
  switch (blockIdx.x) {
    case 0:  W = W1; n = H1_ * NIN_; break;
    case 1:  W = W2; n = H2_ * H1_;  break;
    case 2:  W = Wr; n = H2_ * H2_;  break;
    default: W = W3; n = OUT_ * H2_; break;
  }
  int tid = threadIdx.x;
  float m = 0.f;
  const float4* W4 = (const float4*)W;
  int n4 = n >> 2;
  for (int i = tid; i < n4; i += 256) {
    float4 v = W4[i];
    m = fmaxf(m, fmaxf(fmaxf(fabsf(v.x), fabsf(v.y)), fmaxf(fabsf(v.z), fabsf(v.w))));
  }
  __shared__ float red[256];
  red[tid] = m;
  __syncthreads();
  for (int s = 128; s > 0; s >>= 1) {
    if (tid < s) red[tid] = fmaxf(red[tid], red[tid + s]);
    __syncthreads();
  }
  if (tid == 0) scales[blockIdx.x] = red[0] / 127.0f;
}

// ---------------------------------------------------------------------------
// W1 fake-quant -> fp32 values q*s, TRANSPOSED to [NIN][H1] (k-major) so the
// GEMM's B-stage is a straight coalesced copy.
// ---------------------------------------------------------------------------
__global__ void quant_w1t_k(const float* __restrict__ W1, const float* __restrict__ scales,
                            float* __restrict__ W1qT) {
  int idx = blockIdx.x * 256 + threadIdx.x;   // grid covers exactly NIN_*H1_
  int h = idx & (H1_ - 1);
  int i = idx >> 9;
  float s = scales[0];
  float q = rintf(W1[h * NIN_ + i] / s);
  q = fminf(fmaxf(q, -127.f), 127.f);
  W1qT[idx] = q * s;    // W1qT[i][h]
}

// ---------------------------------------------------------------------------
// Quantize to int8 and TRANSPOSE: W[r][c] (r = out-dim) -> WT[c*rows + r].
// ---------------------------------------------------------------------------
__global__ void quant_t_k(const float* __restrict__ W, const float* __restrict__ scales, int si,
                          signed char* __restrict__ WT, int rows, int cols) {
  int idx = blockIdx.x * 256 + threadIdx.x;
  if (idx >= rows * cols) return;
  int r = idx / cols;
  int c = idx - r * cols;
  float s = scales[si];
  float q = rintf(W[idx] / s);
  q = fminf(fmaxf(q, -127.f), 127.f);
  WT[(size_t)c * rows + r] = (signed char)q;
}

// ---------------------------------------------------------------------------
// Phase A: cur1[t,b,h] = sum_i data[b,i,t] * W1qT[i,h]
// fp32 tiled GEMM, 128x128 tile, BK=16, 256 thr, 8x8/thread.
// Accumulation per output is single-acc, strictly ascending k -> bit-identical
// to the round-1 kernel (which passed with absmax 0).
// ---------------------------------------------------------------------------
__global__ __launch_bounds__(256) void gemm_cur1_k(const float* __restrict__ data,
                                                   const float* __restrict__ W1qT,
                                                   float* __restrict__ cur1) {
  const int b  = blockIdx.y;
  const int t0 = (blockIdx.x >> 2) << 7;
  const int h0 = (blockIdx.x & 3) << 7;
  const int tid = threadIdx.x;

  __shared__ float As[16][128];   // As[k][t]
  __shared__ float Bs[16][128];   // Bs[k][h]

  const int ty = tid >> 4;        // 0..15
  const int tx = tid & 15;        // 0..15

  float acc[8][8];
#pragma unroll
  for (int i = 0; i < 8; i++)
#pragma unroll
    for (int j = 0; j < 8; j++) acc[i][j] = 0.f;

  // two float4 loads per buffer per panel
  const int k0 = tid >> 5;              // 0..7
  const int c0 = (tid & 31) << 2;       // 0..124
  // second load: fi = tid + 256 -> k = k0 + 8, same c0

  const float* dbase = data + (size_t)b * NIN_ * T_;

  for (int kb = 0; kb < NIN_; kb += 16) {
    float4 a0 = *(const float4*)(dbase + (size_t)(kb + k0) * T_ + t0 + c0);
    float4 a1 = *(const float4*)(dbase + (size_t)(kb + k0 + 8) * T_ + t0 + c0);
    float4 b0 = *(const float4*)(W1qT + (size_t)(kb + k0) * H1_ + h0 + c0);
    float4 b1 = *(const float4*)(W1qT + (size_t)(kb + k0 + 8) * H1_ + h0 + c0);
    __syncthreads();
    *(float4*)&As[k0][c0]     = a0;
    *(float4*)&As[k0 + 8][c0] = a1;
    *(float4*)&Bs[k0][c0]     = b0;
    *(float4*)&Bs[k0 + 8][c0] = b1;
    __syncthreads();
#pragma unroll
    for (int k = 0; k < 16; k++) {
      float4 a0v = *(const float4*)&As[k][ty * 4];
      float4 a1v = *(const float4*)&As[k][64 + ty * 4];
      float4 b0v = *(const float4*)&Bs[k][tx * 4];
      float4 b1v = *(const float4*)&Bs[k][64 + tx * 4];
      float a[8] = {a0v.x, a0v.y, a0v.z, a0v.w, a1v.x, a1v.y, a1v.z, a1v.w};
      float w[8] = {b0v.x, b0v.y, b0v.z, b0v.w, b1v.x, b1v.y, b1v.z, b1v.w};
#pragma unroll
      for (int i = 0; i < 8; i++)
#pragma unroll
        for (int j = 0; j < 8; j++)
          acc[i][j] = fmaf(a[i], w[j], acc[i][j]);
    }
  }

  // store: cur1 layout [T, B, H1]
#pragma unroll
  for (int i = 0; i < 8; i++) {
    int row = (i < 4) ? (ty * 4 + i) : (64 + ty * 4 + (i - 4));
    float* op = cur1 + (size_t)(t0 + row) * (B_ * H1_) + (size_t)b * H1_ + h0;
    float4 cA = {acc[i][0], acc[i][1], acc[i][2], acc[i][3]};
    float4 cB = {acc[i][4], acc[i][5], acc[i][6], acc[i][7]};
    *(float4*)(op + tx * 4)      = cA;
    *(float4*)(op + 64 + tx * 4) = cB;
  }
}

// ---------------------------------------------------------------------------
__device__ __forceinline__ void unp_add(unsigned w, int* a) {
  int iw = (int)w;
  a[0] += (iw << 24) >> 24;
  a[1] += (iw << 16) >> 24;
  a[2] += (iw << 8) >> 24;
  a[3] += iw >> 24;
}

// ---------------------------------------------------------------------------
// Phase B: sequential SNN recurrence. One block per batch row, 512 threads.
// Dword gathers: thread (g=tid>>7, c=tid&127) accumulates postsyn columns
// 4c..4c+3 over listed rows k = g, g+4, ... Exact integer partials reduced in
// LDS -> h math bit-identical to round 1. W3T lives in LDS.
// ---------------------------------------------------------------------------
__global__ __launch_bounds__(512) void recurrent_k(
    const float* __restrict__ cur1,        // [T, B, H1]
    const signed char* __restrict__ W2T,   // [H1][H2] presyn-major
    const signed char* __restrict__ WrT,   // [H2][H2]
    const signed char* __restrict__ W3T,   // [H2][OUT]
    const float* __restrict__ scales,
    const float* __restrict__ beta1p, const float* __restrict__ th1p,
    const float* __restrict__ betarp, const float* __restrict__ thrp,
    const float* __restrict__ beta2p, const float* __restrict__ th2p,
    float* __restrict__ out)               // [T, B, OUT]
{
  const int b = blockIdx.x;
  const int tid = threadIdx.x;

  const float s2sc = scales[1];
  const float srsc = scales[2];
  const float s3sc = scales[3];
  const float b1 = fminf(fmaxf(beta1p[0], 0.f), 1.f);
  const float br = fminf(fmaxf(betarp[0], 0.f), 1.f);
  const float b2 = fminf(fmaxf(beta2p[0], 0.f), 1.f);
  const float th1 = th1p[0], thr = thrp[0], th2 = th2p[0];

  const unsigned* W2T4 = (const unsigned*)W2T;   // [H1][128]
  const unsigned* WrT4 = (const unsigned*)WrT;   // [H2][128]

  __shared__ unsigned W3L[H2_ * (OUT_ / 4)];     // 64 KB: [H2][32] dwords
  __shared__ int red2[4][H2_];                   // 8 KB
  __shared__ int redr[4][H2_];                   // 8 KB
  __shared__ int red3[16][OUT_];                 // 8 KB
  __shared__ int list1[H1_];                     // 2 KB
  __shared__ int lr[2][H2_];                     // 4 KB
  __shared__ int n1s, nrc[2];

  // preload W3T into LDS (16384 dwords)
  {
    const uint4* src = (const uint4*)W3T;
    uint4* dst = (uint4*)W3L;
    for (int i = tid; i < H2_ * (OUT_ / 4) / 4; i += 512) dst[i] = src[i];
  }
  if (tid == 0) { n1s = 0; nrc[0] = 0; nrc[1] = 0; }
  __syncthreads();

  float m1 = 0.f, mr = 0.f, m2 = 0.f;
  float sr_own = 0.f;

  const int g  = tid >> 7;       // 0..3   row-group for H2 gathers
  const int c  = tid & 127;      // 0..127 dword column
  const int g3 = tid >> 5;       // 0..15  row-group for W3 gather
  const int c3 = tid & 31;       // 0..31  dword column (OUT/4)

  for (int t = 0; t < T_; t++) {
    const int old = t & 1;
    const int nxt = old ^ 1;

    // ---- A: layer-1 LIF + spike list ----
    if (tid == 0) nrc[nxt] = 0;
    float cin = cur1[((size_t)t * B_ + b) * H1_ + tid];
    m1 = b1 * m1 + cin;
    if (m1 - th1 > 0.f) {
      int p = atomicAdd(&n1s, 1);
      list1[p] = tid;
      m1 = 0.f;
    }
    __syncthreads();                               // S1
    const int n1 = n1s;
    const int nr = nrc[old];
    const int* lrold = lr[old];
    int* lrnew = lr[nxt];

    // ---- B: dword gathers ----
    int a2[4] = {0, 0, 0, 0};
    {
      int k = g;
      for (; k + 28 < n1; k += 32) {
        int i0 = list1[k],      i1 = list1[k + 4],  i2 = list1[k + 8],  i3 = list1[k + 12];
        int i4 = list1[k + 16], i5 = list1[k + 20], i6 = list1[k + 24], i7 = list1[k + 28];
        unsigned w0 = W2T4[(i0 << 7) + c], w1 = W2T4[(i1 << 7) + c];
        unsigned w2 = W2T4[(i2 << 7) + c], w3 = W2T4[(i3 << 7) + c];
        unsigned w4 = W2T4[(i4 << 7) + c], w5 = W2T4[(i5 << 7) + c];
        unsigned w6 = W2T4[(i6 << 7) + c], w7 = W2T4[(i7 << 7) + c];
        unp_add(w0, a2); unp_add(w1, a2); unp_add(w2, a2); unp_add(w3, a2);
        unp_add(w4, a2); unp_add(w5, a2); unp_add(w6, a2); unp_add(w7, a2);
      }
      for (; k < n1; k += 4) unp_add(W2T4[(list1[k] << 7) + c], a2);
    }
    int ar[4] = {0, 0, 0, 0};
    {
      int k = g;
      for (; k + 28 < nr; k += 32) {
        int i0 = lrold[k],      i1 = lrold[k + 4],  i2 = lrold[k + 8],  i3 = lrold[k + 12];
        int i4 = lrold[k + 16], i5 = lrold[k + 20], i6 = lrold[k + 24], i7 = lrold[k + 28];
        unsigned w0 = WrT4[(i0 << 7) + c], w1 = WrT4[(i1 << 7) + c];
        unsigned w2 = WrT4[(i2 << 7) + c], w3 = WrT4[(i3 << 7) + c];
        unsigned w4 = WrT4[(i4 << 7) + c], w5 = WrT4[(i5 << 7) + c];
        unsigned w6 = WrT4[(i6 << 7) + c], w7 = WrT4[(i7 << 7) + c];
        unp_add(w0, ar); unp_add(w1, ar); unp_add(w2, ar); unp_add(w3, ar);
        unp_add(w4, ar); unp_add(w5, ar); unp_add(w6, ar); unp_add(w7, ar);
      }
      for (; k < nr; k += 4) unp_add(WrT4[(lrold[k] << 7) + c], ar);
    }
    *(int4*)&red2[g][c << 2] = make_int4(a2[0], a2[1], a2[2], a2[3]);
    *(int4*)&redr[g][c << 2] = make_int4(ar[0], ar[1], ar[2], ar[3]);
    __syncthreads();                               // S2

    // ---- C: h reduce (exact int), recurrent LIF, new spike list ----
    int acc2 = red2[0][tid] + red2[1][tid] + red2[2][tid] + red2[3][tid];
    int accr = redr[0][tid] + redr[1][tid] + redr[2][tid] + redr[3][tid];
    float h = s2sc * (float)acc2 + srsc * (float)accr;
    mr = (br * mr + h) * (1.f - sr_own);
    sr_own = (mr - thr > 0.f) ? 1.f : 0.f;
    if (sr_own != 0.f) {
      int p = atomicAdd(&nrc[nxt], 1);
      lrnew[p] = tid;
    }
    if (tid == 511) n1s = 0;                       // n1 already captured post-S1
    __syncthreads();                               // S3
    const int nr2 = nrc[nxt];

    // ---- D: W3 gather from LDS ----
    int a3[4] = {0, 0, 0, 0};
    {
      int k = g3;
      for (; k + 48 < nr2; k += 64) {
        int j0 = lrnew[k], j1 = lrnew[k + 16], j2 = lrnew[k + 32], j3 = lrnew[k + 48];
        unsigned w0 = W3L[(j0 << 5) + c3], w1 = W3L[(j1 << 5) + c3];
        unsigned w2 = W3L[(j2 << 5) + c3], w3 = W3L[(j3 << 5) + c3];
        unp_add(w0, a3); unp_add(w1, a3); unp_add(w2, a3); unp_add(w3, a3);
      }
      for (; k < nr2; k += 16) unp_add(W3L[(lrnew[k] << 5) + c3], a3);
    }
    *(int4*)&red3[g3][c3 << 2] = make_int4(a3[0], a3[1], a3[2], a3[3]);
    __syncthreads();                               // S4

    // ---- E: layer-2 LIF + output ----
    if (tid < OUT_) {
      int acc3 = 0;
#pragma unroll
      for (int q = 0; q < 16; q++) acc3 += red3[q][tid];
      float cur3 = s3sc * (float)acc3;
      m2 = b2 * m2 + cur3;
      float spk = (m2 - th2 > 0.f) ? 1.f : 0.f;
      m2 *= (1.f - spk);
      out[((size_t)t * B_ + b) * OUT_ + tid] = spk;
    }
  }
}

// ---------------------------------------------------------------------------
extern "C" void kernel_launch(void* const* d_in, const int* in_sizes, int n_in,
                              void* d_out, int out_size, void* d_ws, size_t ws_size,
                              hipStream_t stream) {
  const float* data  = (const float*)d_in[0];
  const float* W1    = (const float*)d_in[1];
  const float* W2    = (const float*)d_in[2];
  const float* Wr    = (const float*)d_in[3];
  const float* W3    = (const float*)d_in[4];
  const float* beta1 = (const float*)d_in[5];
  const float* th1   = (const float*)d_in[6];
  const float* betar = (const float*)d_in[7];
  const float* thr   = (const float*)d_in[8];
  const float* beta2 = (const float*)d_in[9];
  const float* th2   = (const float*)d_in[10];

  char* ws = (char*)d_ws;
  float*       scales = (float*)ws;                              // 4 floats
  float*       W1qT   = (float*)(ws + 256);                      // 1 MB [NIN][H1]
  signed char* W2T    = (signed char*)(ws + 256 + 1048576);      // 256 KB
  signed char* WrT    = W2T + (size_t)H1_ * H2_;                 // 256 KB
  signed char* W3T    = WrT + (size_t)H2_ * H2_;                 // 64 KB
  float*       cur1   = (float*)(ws + 256 + 1048576
                                 + (size_t)H1_ * H2_ + (size_t)H2_ * H2_
                                 + (size_t)H2_ * OUT_);          // 128 MB [T,B,H1]

  hipLaunchKernelGGL(absmax_k, dim3(4), dim3(256), 0, stream, W1, W2, Wr, W3, scales);
  hipLaunchKernelGGL(quant_w1t_k, dim3((H1_ * NIN_) / 256), dim3(256), 0, stream, W1, scales, W1qT);
  hipLaunchKernelGGL(quant_t_k, dim3((H2_ * H1_) / 256), dim3(256), 0, stream, W2, scales, 1, W2T, H2_, H1_);
  hipLaunchKernelGGL(quant_t_k, dim3((H2_ * H2_) / 256), dim3(256), 0, stream, Wr, scales, 2, WrT, H2_, H2_);
  hipLaunchKernelGGL(quant_t_k, dim3((OUT_ * H2_) / 256), dim3(256), 0, stream, W3, scales, 3, W3T, OUT_, H2_);
  hipLaunchKernelGGL(gemm_cur1_k, dim3(8, 256), dim3(256), 0, stream, data, W1qT, cur1);
  hipLaunchKernelGGL(recurrent_k, dim3(256), dim3(512), 0, stream, cur1, W2T, WrT, W3T, scales,
                     beta1, th1, betar, thr, beta2, th2, (float*)d_out);
}

// Round 3
// 1202.274 us; speedup vs baseline: 1.3343x; 1.0626x over previous
//
#include <hip/hip_runtime.h>

#define B_   256
#define NIN_ 512
#define T_   256
#define H1_  512
#define H2_  512
#define OUT_ 128

typedef __attribute__((ext_vector_type(8))) short bf16x8;
typedef __attribute__((ext_vector_type(4))) float f32x4;

// ---------------------------------------------------------------------------
// Per-tensor absmax -> scale = max|W|/127.  One block per tensor.
// ---------------------------------------------------------------------------
__global__ void absmax_k(const float* __restrict__ W1, const float* __restrict__ W2,
                         const float* __restrict__ Wr, const float* __restrict__ W3,
                         float* __restrict__ scales) {
  const float* W; int n;
  switch (blockIdx.x) {
    case 0:  W = W1; n = H1_ * NIN_; break;
    case 1:  W = W2; n = H2_ * H1_;  break;
    case 2:  W = Wr; n = H2_ * H2_;  break;
    default: W = W3; n = OUT_ * H2_; break;
  }
  int tid = threadIdx.x;
  float m = 0.f;
  const float4* W4 = (const float4*)W;
  int n4 = n >> 2;
  for (int i = tid; i < n4; i += 256) {
    float4 v = W4[i];
    m = fmaxf(m, fmaxf(fmaxf(fabsf(v.x), fabsf(v.y)), fmaxf(fabsf(v.z), fabsf(v.w))));
  }
  __shared__ float red[256];
  red[tid] = m;
  __syncthreads();
  for (int s = 128; s > 0; s >>= 1) {
    if (tid < s) red[tid] = fmaxf(red[tid], red[tid + s]);
    __syncthreads();
  }
  if (tid == 0) scales[blockIdx.x] = red[0] / 127.0f;
}

// ---------------------------------------------------------------------------
// W1 fake-quant -> fp32 q*s, transposed to [NIN][H1] for the fp32 GEMM.
// ---------------------------------------------------------------------------
__global__ void quant_w1t_k(const float* __restrict__ W1, const float* __restrict__ scales,
                            float* __restrict__ W1qT) {
  int idx = blockIdx.x * 256 + threadIdx.x;
  int h = idx & (H1_ - 1);
  int i = idx >> 9;
  float s = scales[0];
  float q = rintf(W1[h * NIN_ + i] / s);
  q = fminf(fmaxf(q, -127.f), 127.f);
  W1qT[idx] = q * s;
}

// ---------------------------------------------------------------------------
// Quantize to int8 + transpose (presyn-major) — used for Wr (recurrent gather).
// ---------------------------------------------------------------------------
__global__ void quant_t_k(const float* __restrict__ W, const float* __restrict__ scales, int si,
                          signed char* __restrict__ WT, int rows, int cols) {
  int idx = blockIdx.x * 256 + threadIdx.x;
  if (idx >= rows * cols) return;
  int r = idx / cols;
  int c = idx - r * cols;
  float s = scales[si];
  float q = rintf(W[idx] / s);
  q = fminf(fmaxf(q, -127.f), 127.f);
  WT[(size_t)c * rows + r] = (signed char)q;
}

// ---------------------------------------------------------------------------
// Quantize to bf16 integers, same orientation (row-major [rows][cols]).
// q in [-127,127] integer -> bf16 exact (<=7 mantissa bits).
// ---------------------------------------------------------------------------
__global__ void quant_bf_k(const float* __restrict__ W, const float* __restrict__ scales,
                           int si, ushort* __restrict__ out, int n) {
  int idx = blockIdx.x * 256 + threadIdx.x;
  if (idx >= n) return;
  float s = scales[si];
  float q = rintf(W[idx] / s);
  q = fminf(fmaxf(q, -127.f), 127.f);
  out[idx] = (ushort)(__float_as_uint(q) >> 16);
}

// ---------------------------------------------------------------------------
// Phase A: cur1[t,b,h] = sum_i data[b,i,t] * W1qT[i,h].  fp32, 128x128 tile,
// BK=16, double-buffered LDS (1 barrier/iter).  FMA order identical to the
// round-1/2 kernel (ascending k, single accumulator) -> bit-identical cur1.
// ---------------------------------------------------------------------------
__global__ __launch_bounds__(256) void gemm_cur1_k(const float* __restrict__ data,
                                                   const float* __restrict__ W1qT,
                                                   float* __restrict__ cur1) {
  const int b  = blockIdx.y;
  const int t0 = (blockIdx.x >> 2) << 7;
  const int h0 = (blockIdx.x & 3) << 7;
  const int tid = threadIdx.x;

  __shared__ float As[2][16][128];
  __shared__ float Bs[2][16][128];

  const int ty = tid >> 4, tx = tid & 15;
  float acc[8][8];
#pragma unroll
  for (int i = 0; i < 8; i++)
#pragma unroll
    for (int j = 0; j < 8; j++) acc[i][j] = 0.f;

  const int k0 = tid >> 5;
  const int c0 = (tid & 31) << 2;
  const float* dbase = data + (size_t)b * NIN_ * T_;

  float4 a0 = *(const float4*)(dbase + (size_t)k0 * T_ + t0 + c0);
  float4 a1 = *(const float4*)(dbase + (size_t)(k0 + 8) * T_ + t0 + c0);
  float4 b0 = *(const float4*)(W1qT + (size_t)k0 * H1_ + h0 + c0);
  float4 b1 = *(const float4*)(W1qT + (size_t)(k0 + 8) * H1_ + h0 + c0);
  *(float4*)&As[0][k0][c0]     = a0;
  *(float4*)&As[0][k0 + 8][c0] = a1;
  *(float4*)&Bs[0][k0][c0]     = b0;
  *(float4*)&Bs[0][k0 + 8][c0] = b1;
  __syncthreads();

  for (int it = 0; it < 32; it++) {
    const int cur = it & 1;
    if (it < 31) {
      int kb = (it + 1) << 4;
      a0 = *(const float4*)(dbase + (size_t)(kb + k0) * T_ + t0 + c0);
      a1 = *(const float4*)(dbase + (size_t)(kb + k0 + 8) * T_ + t0 + c0);
      b0 = *(const float4*)(W1qT + (size_t)(kb + k0) * H1_ + h0 + c0);
      b1 = *(const float4*)(W1qT + (size_t)(kb + k0 + 8) * H1_ + h0 + c0);
    }
#pragma unroll
    for (int k = 0; k < 16; k++) {
      float4 A0 = *(const float4*)&As[cur][k][ty * 4];
      float4 A1 = *(const float4*)&As[cur][k][64 + ty * 4];
      float4 B0 = *(const float4*)&Bs[cur][k][tx * 4];
      float4 B1 = *(const float4*)&Bs[cur][k][64 + tx * 4];
      float a[8] = {A0.x, A0.y, A0.z, A0.w, A1.x, A1.y, A1.z, A1.w};
      float w[8] = {B0.x, B0.y, B0.z, B0.w, B1.x, B1.y, B1.z, B1.w};
#pragma unroll
      for (int i = 0; i < 8; i++)
#pragma unroll
        for (int j = 0; j < 8; j++)
          acc[i][j] = fmaf(a[i], w[j], acc[i][j]);
    }
    if (it < 31) {
      const int nb = cur ^ 1;
      *(float4*)&As[nb][k0][c0]     = a0;
      *(float4*)&As[nb][k0 + 8][c0] = a1;
      *(float4*)&Bs[nb][k0][c0]     = b0;
      *(float4*)&Bs[nb][k0 + 8][c0] = b1;
    }
    __syncthreads();
  }

#pragma unroll
  for (int i = 0; i < 8; i++) {
    int row = (i < 4) ? (ty * 4 + i) : (64 + ty * 4 + (i - 4));
    float* op = cur1 + (size_t)(t0 + row) * (B_ * H1_) + (size_t)b * H1_ + h0;
    float4 cA = {acc[i][0], acc[i][1], acc[i][2], acc[i][3]};
    float4 cB = {acc[i][4], acc[i][5], acc[i][6], acc[i][7]};
    *(float4*)(op + tx * 4)      = cA;
    *(float4*)(op + 64 + tx * 4) = cB;
  }
}

// ---------------------------------------------------------------------------
// scan1: parallel per-neuron layer-1 LIF scan.  Op order identical to round 2.
// n = b*H1 + h;  reads cur1[t][n] (coalesced), writes uchar spike raster.
// ---------------------------------------------------------------------------
__global__ __launch_bounds__(256) void scan1_k(const float* __restrict__ cur1,
                                               unsigned char* __restrict__ s1u,
                                               const float* __restrict__ beta1p,
                                               const float* __restrict__ th1p) {
  const int n = blockIdx.x * 256 + threadIdx.x;
  const float b1 = fminf(fmaxf(beta1p[0], 0.f), 1.f);
  const float th1 = th1p[0];
  const size_t S = (size_t)B_ * H1_;
  float m1 = 0.f;
  for (int t = 0; t < T_; t += 4) {
    float c0 = cur1[(size_t)t * S + n];
    float c1 = cur1[(size_t)(t + 1) * S + n];
    float c2 = cur1[(size_t)(t + 2) * S + n];
    float c3 = cur1[(size_t)(t + 3) * S + n];
    m1 = b1 * m1 + c0; bool s0 = m1 - th1 > 0.f; if (s0) m1 = 0.f;
    s1u[(size_t)t * S + n] = s0;
    m1 = b1 * m1 + c1; bool s1 = m1 - th1 > 0.f; if (s1) m1 = 0.f;
    s1u[(size_t)(t + 1) * S + n] = s1;
    m1 = b1 * m1 + c2; bool s2 = m1 - th1 > 0.f; if (s2) m1 = 0.f;
    s1u[(size_t)(t + 2) * S + n] = s2;
    m1 = b1 * m1 + c3; bool s3 = m1 - th1 > 0.f; if (s3) m1 = 0.f;
    s1u[(size_t)(t + 3) * S + n] = s3;
  }
}

// ---------------------------------------------------------------------------
// Spike GEMM via bf16 MFMA (exact: spikes 0/1, weights integer <=127, all
// partial sums < 2^24 -> fp32 accumulation exact == integer gather).
// C[m][n] = sum_k A8[m][k] * Bw[n][k];  A8 uchar [M][512], Bw bf16 [N][512].
// Tile 128x128, BK=64, 256 threads (4 waves), per wave: 2 msub x 8 nsub.
// ---------------------------------------------------------------------------
__global__ __launch_bounds__(256) void gemm_spk_k(const unsigned char* __restrict__ A8,
                                                  const ushort* __restrict__ Bw,
                                                  float* __restrict__ C, int N) {
  __shared__ short As[128 * 72];   // [row][64+8 pad] bf16
  __shared__ short Bs[128 * 72];
  const int tid = threadIdx.x;
  const int m0 = blockIdx.y << 7;
  const int n0 = blockIdx.x << 7;
  const int lane = tid & 63, wave = tid >> 6;
  const int quad = lane >> 4, lm = lane & 15;
  const int wm = wave << 5;

  f32x4 acc[2][8];
#pragma unroll
  for (int s = 0; s < 2; s++)
#pragma unroll
    for (int n = 0; n < 8; n++) acc[s][n] = (f32x4){0.f, 0.f, 0.f, 0.f};

  for (int kb = 0; kb < 512; kb += 64) {
    uint4 av[2], bv[4];
#pragma unroll
    for (int i = 0; i < 2; i++) {
      int ch = tid + (i << 8);
      int row = ch >> 2, offB = (ch & 3) << 4;
      av[i] = *(const uint4*)(A8 + (size_t)(m0 + row) * 512 + kb + offB);
    }
#pragma unroll
    for (int i = 0; i < 4; i++) {
      int ch = tid + (i << 8);
      int row = ch >> 3, off = (ch & 7) << 3;
      bv[i] = *(const uint4*)(Bw + (size_t)(n0 + row) * 512 + kb + off);
    }
    __syncthreads();
#pragma unroll
    for (int i = 0; i < 2; i++) {
      int ch = tid + (i << 8);
      int row = ch >> 2, offB = (ch & 3) << 4;
      unsigned u[4] = {av[i].x, av[i].y, av[i].z, av[i].w};
      unsigned d[8];
#pragma unroll
      for (int w = 0; w < 4; w++) {
        unsigned uu = u[w];
        d[2 * w]     = ((uu & 1u) | ((uu & 0x100u) << 8)) * 0x3F80u;
        d[2 * w + 1] = (((uu >> 16) & 1u) | ((uu & 0x1000000u) >> 8)) * 0x3F80u;
      }
      uint4* dst = (uint4*)&As[row * 72 + offB];
      dst[0] = make_uint4(d[0], d[1], d[2], d[3]);
      dst[1] = make_uint4(d[4], d[5], d[6], d[7]);
    }
#pragma unroll
    for (int i = 0; i < 4; i++) {
      int ch = tid + (i << 8);
      int row = ch >> 3, off = (ch & 7) << 3;
      *(uint4*)&Bs[row * 72 + off] = bv[i];
    }
    __syncthreads();
#pragma unroll
    for (int kc = 0; kc < 64; kc += 32) {
      bf16x8 af0 = *(const bf16x8*)&As[(wm + lm) * 72 + kc + quad * 8];
      bf16x8 af1 = *(const bf16x8*)&As[(wm + 16 + lm) * 72 + kc + quad * 8];
      bf16x8 bfr[8];
#pragma unroll
      for (int n = 0; n < 8; n++)
        bfr[n] = *(const bf16x8*)&Bs[((n << 4) + lm) * 72 + kc + quad * 8];
#pragma unroll
      for (int n = 0; n < 8; n++) {
        acc[0][n] = __builtin_amdgcn_mfma_f32_16x16x32_bf16(af0, bfr[n], acc[0][n], 0, 0, 0);
        acc[1][n] = __builtin_amdgcn_mfma_f32_16x16x32_bf16(af1, bfr[n], acc[1][n], 0, 0, 0);
      }
    }
    __syncthreads();
  }

#pragma unroll
  for (int s = 0; s < 2; s++)
#pragma unroll
    for (int n = 0; n < 8; n++) {
      int row = m0 + wm + (s << 4) + quad * 4;
      int col = n0 + (n << 4) + lm;
#pragma unroll
      for (int r = 0; r < 4; r++)
        C[(size_t)(row + r) * N + col] = acc[s][n][r];
    }
}

// ---------------------------------------------------------------------------
__device__ __forceinline__ void unp_add(unsigned w, int* a) {
  int iw = (int)w;
  a[0] += (iw << 24) >> 24;
  a[1] += (iw << 16) >> 24;
  a[2] += (iw << 8) >> 24;
  a[3] += iw >> 24;
}

// ---------------------------------------------------------------------------
// Sequential recurrent layer only.  One block per batch row, 1024 threads.
// h = s2sc*cur2a[t][b][u] + srsc*(sum over active presyn of WrT) — exact ints.
// ---------------------------------------------------------------------------
__global__ __launch_bounds__(1024) void recurrent_k(
    const float* __restrict__ cur2a,       // [T*B, H2] exact integer sums (fp32)
    const signed char* __restrict__ WrT,   // [H2][H2] presyn-major
    unsigned char* __restrict__ sru,       // [T*B, H2] spike raster
    const float* __restrict__ scales,
    const float* __restrict__ betarp, const float* __restrict__ thrp) {
  const int b = blockIdx.x;
  const int tid = threadIdx.x;
  const float s2sc = scales[1];
  const float srsc = scales[2];
  const float br = fminf(fmaxf(betarp[0], 0.f), 1.f);
  const float thr = thrp[0];

  const unsigned* WrT4 = (const unsigned*)WrT;   // [H2][128] dwords

  __shared__ int red[8][H2_];     // 16 KB
  __shared__ int lst[2][H2_];     // 4 KB
  __shared__ int nc[2];

  if (tid < 2) nc[tid] = 0;
  __syncthreads();

  float mr = 0.f, sr_own = 0.f;
  const int g = tid >> 7;        // 0..7
  const int c = tid & 127;       // dword column

  for (int t = 0; t < T_; t++) {
    const int old = t & 1, nxt = old ^ 1;
    float c2 = 0.f;
    if (tid < H2_) c2 = cur2a[((size_t)t * B_ + b) * H2_ + tid];  // issued early
    if (tid == 1023) nc[nxt] = 0;   // safe: this phase only reads nc[old]
    const int n = nc[old];
    const int* L = lst[old];

    int a4[4] = {0, 0, 0, 0};
    int k = g;
    for (; k + 56 < n; k += 64) {
      int i0 = L[k],      i1 = L[k + 8],  i2 = L[k + 16], i3 = L[k + 24];
      int i4 = L[k + 32], i5 = L[k + 40], i6 = L[k + 48], i7 = L[k + 56];
      unsigned w0 = WrT4[(i0 << 7) + c], w1 = WrT4[(i1 << 7) + c];
      unsigned w2 = WrT4[(i2 << 7) + c], w3 = WrT4[(i3 << 7) + c];
      unsigned w4 = WrT4[(i4 << 7) + c], w5 = WrT4[(i5 << 7) + c];
      unsigned w6 = WrT4[(i6 << 7) + c], w7 = WrT4[(i7 << 7) + c];
      unp_add(w0, a4); unp_add(w1, a4); unp_add(w2, a4); unp_add(w3, a4);
      unp_add(w4, a4); unp_add(w5, a4); unp_add(w6, a4); unp_add(w7, a4);
    }
    for (; k + 24 < n; k += 32) {
      int i0 = L[k], i1 = L[k + 8], i2 = L[k + 16], i3 = L[k + 24];
      unsigned w0 = WrT4[(i0 << 7) + c], w1 = WrT4[(i1 << 7) + c];
      unsigned w2 = WrT4[(i2 << 7) + c], w3 = WrT4[(i3 << 7) + c];
      unp_add(w0, a4); unp_add(w1, a4); unp_add(w2, a4); unp_add(w3, a4);
    }
    for (; k < n; k += 8) unp_add(WrT4[(L[k] << 7) + c], a4);
    *(int4*)&red[g][c << 2] = make_int4(a4[0], a4[1], a4[2], a4[3]);
    __syncthreads();                               // S1

    if (tid < H2_) {
      int acc = red[0][tid] + red[1][tid] + red[2][tid] + red[3][tid]
              + red[4][tid] + red[5][tid] + red[6][tid] + red[7][tid];
      float h = s2sc * c2 + srsc * (float)acc;
      mr = (br * mr + h) * (1.f - sr_own);
      sr_own = (mr - thr > 0.f) ? 1.f : 0.f;
      sru[((size_t)t * B_ + b) * H2_ + tid] = (unsigned char)(sr_own != 0.f);
      if (sr_own != 0.f) {
        int p = atomicAdd(&nc[nxt], 1);
        lst[nxt][p] = tid;
      }
    }
    __syncthreads();                               // S2
  }
}

// ---------------------------------------------------------------------------
// scan3: parallel layer-2 LIF scan over precomputed cur3 sums.
// ---------------------------------------------------------------------------
__global__ __launch_bounds__(256) void scan3_k(const float* __restrict__ cur3,
                                               float* __restrict__ out,
                                               const float* __restrict__ scales,
                                               const float* __restrict__ beta2p,
                                               const float* __restrict__ th2p) {
  const int n = blockIdx.x * 256 + threadIdx.x;   // 32768 = B*OUT
  const float s3sc = scales[3];
  const float b2 = fminf(fmaxf(beta2p[0], 0.f), 1.f);
  const float th2 = th2p[0];
  const size_t S = (size_t)B_ * OUT_;
  float m2 = 0.f;
  for (int t = 0; t < T_; t += 4) {
    float v0 = cur3[(size_t)t * S + n];
    float v1 = cur3[(size_t)(t + 1) * S + n];
    float v2 = cur3[(size_t)(t + 2) * S + n];
    float v3 = cur3[(size_t)(t + 3) * S + n];
    m2 = b2 * m2 + s3sc * v0; float p0 = (m2 - th2 > 0.f) ? 1.f : 0.f; m2 *= (1.f - p0);
    out[(size_t)t * S + n] = p0;
    m2 = b2 * m2 + s3sc * v1; float p1 = (m2 - th2 > 0.f) ? 1.f : 0.f; m2 *= (1.f - p1);
    out[(size_t)(t + 1) * S + n] = p1;
    m2 = b2 * m2 + s3sc * v2; float p2 = (m2 - th2 > 0.f) ? 1.f : 0.f; m2 *= (1.f - p2);
    out[(size_t)(t + 2) * S + n] = p2;
    m2 = b2 * m2 + s3sc * v3; float p3 = (m2 - th2 > 0.f) ? 1.f : 0.f; m2 *= (1.f - p3);
    out[(size_t)(t + 3) * S + n] = p3;
  }
}

// ---------------------------------------------------------------------------
extern "C" void kernel_launch(void* const* d_in, const int* in_sizes, int n_in,
                              void* d_out, int out_size, void* d_ws, size_t ws_size,
                              hipStream_t stream) {
  const float* data  = (const float*)d_in[0];
  const float* W1    = (const float*)d_in[1];
  const float* W2    = (const float*)d_in[2];
  const float* Wr    = (const float*)d_in[3];
  const float* W3    = (const float*)d_in[4];
  const float* beta1 = (const float*)d_in[5];
  const float* th1   = (const float*)d_in[6];
  const float* betar = (const float*)d_in[7];
  const float* thr   = (const float*)d_in[8];
  const float* beta2 = (const float*)d_in[9];
  const float* th2   = (const float*)d_in[10];

  char* ws = (char*)d_ws;
  float*         scales = (float*)ws;                         // @0
  float*         W1qT   = (float*)(ws + 4096);                // 1 MB
  ushort*        W2bf   = (ushort*)(ws + 4096 + 1048576);     // 512 KB [H2][H1]
  ushort*        W3bf   = (ushort*)(ws + 4096 + 1048576 + 524288);          // 128 KB [OUT][H2]
  signed char*   WrT    = (signed char*)(ws + 4096 + 1048576 + 524288 + 131072); // 256 KB
  // region A (128 MB): cur1 -> (dead after scan1) cur2a -> (dead after recurrent) cur3
  float*         regA   = (float*)(ws + (size_t)4194304);
  // region B (32 MB): s1u -> (dead after gemm2... reused) sru
  unsigned char* regB   = (unsigned char*)(ws + (size_t)4194304 + 134217728);

  float* cur1 = regA;
  float* cur2a = regA;
  float* cur3 = regA;
  unsigned char* s1u = regB;
  unsigned char* sru = regB + (size_t)33554432;  // separate: gemm2 reads s1u while nothing writes B; sru written later

  hipLaunchKernelGGL(absmax_k, dim3(4), dim3(256), 0, stream, W1, W2, Wr, W3, scales);
  hipLaunchKernelGGL(quant_w1t_k, dim3((H1_ * NIN_) / 256), dim3(256), 0, stream, W1, scales, W1qT);
  hipLaunchKernelGGL(quant_bf_k, dim3((H2_ * H1_) / 256), dim3(256), 0, stream, W2, scales, 1, W2bf, H2_ * H1_);
  hipLaunchKernelGGL(quant_t_k, dim3((H2_ * H2_) / 256), dim3(256), 0, stream, Wr, scales, 2, WrT, H2_, H2_);
  hipLaunchKernelGGL(quant_bf_k, dim3((OUT_ * H2_) / 256), dim3(256), 0, stream, W3, scales, 3, W3bf, OUT_ * H2_);
  // cur1 = data x W1q^T  (fp32, bit-identical to rounds 1-2)
  hipLaunchKernelGGL(gemm_cur1_k, dim3(8, 256), dim3(256), 0, stream, data, W1qT, cur1);
  // s1 raster
  hipLaunchKernelGGL(scan1_k, dim3((B_ * H1_) / 256), dim3(256), 0, stream, cur1, s1u, beta1, th1);
  // cur2a = s1 @ W2q^T (exact integer sums via bf16 MFMA); overwrites cur1 (dead)
  hipLaunchKernelGGL(gemm_spk_k, dim3(4, 512), dim3(256), 0, stream, s1u, W2bf, cur2a, H2_);
  // sequential recurrent layer
  hipLaunchKernelGGL(recurrent_k, dim3(256), dim3(1024), 0, stream, cur2a, WrT, sru, scales, betar, thr);
  // cur3 = sr @ W3q^T; overwrites cur2a (dead)
  hipLaunchKernelGGL(gemm_spk_k, dim3(1, 512), dim3(256), 0, stream, sru, W3bf, cur3, OUT_);
  // layer-2 scan -> output spikes
  hipLaunchKernelGGL(scan3_k, dim3((B_ * OUT_) / 256), dim3(256), 0, stream, cur3, d_out ? (float*)d_out : (float*)d_out, scales, beta2, th2);
}

// Round 5
// 1058.687 us; speedup vs baseline: 1.5152x; 1.1356x over previous
//
#include <hip/hip_runtime.h>

#define B_   256
#define NIN_ 512
#define T_   256
#define H1_  512
#define H2_  512
#define OUT_ 128

typedef __attribute__((ext_vector_type(8))) short bf16x8;
typedef __attribute__((ext_vector_type(4))) float f32x4;
typedef __attribute__((address_space(1))) const unsigned int* gl_cu;
typedef __attribute__((address_space(3))) unsigned int* ls_u;

// ---------------------------------------------------------------------------
// Per-tensor absmax -> scale = max|W|/127.  One block per tensor.
// ---------------------------------------------------------------------------
__global__ void absmax_k(const float* __restrict__ W1, const float* __restrict__ W2,
                         const float* __restrict__ Wr, const float* __restrict__ W3,
                         float* __restrict__ scales) {
  const float* W; int n;
  switch (blockIdx.x) {
    case 0:  W = W1; n = H1_ * NIN_; break;
    case 1:  W = W2; n = H2_ * H1_;  break;
    case 2:  W = Wr; n = H2_ * H2_;  break;
    default: W = W3; n = OUT_ * H2_; break;
  }
  int tid = threadIdx.x;
  float m = 0.f;
  const float4* W4 = (const float4*)W;
  int n4 = n >> 2;
  for (int i = tid; i < n4; i += 256) {
    float4 v = W4[i];
    m = fmaxf(m, fmaxf(fmaxf(fabsf(v.x), fabsf(v.y)), fmaxf(fabsf(v.z), fabsf(v.w))));
  }
  __shared__ float red[256];
  red[tid] = m;
  __syncthreads();
  for (int s = 128; s > 0; s >>= 1) {
    if (tid < s) red[tid] = fmaxf(red[tid], red[tid + s]);
    __syncthreads();
  }
  if (tid == 0) scales[blockIdx.x] = red[0] / 127.0f;
}

// ---------------------------------------------------------------------------
// W1 fake-quant -> fp32 q*s, transposed to [NIN][H1] for the fp32 GEMM.
// ---------------------------------------------------------------------------
__global__ void quant_w1t_k(const float* __restrict__ W1, const float* __restrict__ scales,
                            float* __restrict__ W1qT) {
  int idx = blockIdx.x * 256 + threadIdx.x;
  int h = idx & (H1_ - 1);
  int i = idx >> 9;
  float s = scales[0];
  float q = rintf(W1[h * NIN_ + i] / s);
  q = fminf(fmaxf(q, -127.f), 127.f);
  W1qT[idx] = q * s;
}

// ---------------------------------------------------------------------------
// Quantize to int8 + transpose (presyn-major) — used for Wr (recurrent gather).
// ---------------------------------------------------------------------------
__global__ void quant_t_k(const float* __restrict__ W, const float* __restrict__ scales, int si,
                          signed char* __restrict__ WT, int rows, int cols) {
  int idx = blockIdx.x * 256 + threadIdx.x;
  if (idx >= rows * cols) return;
  int r = idx / cols;
  int c = idx - r * cols;
  float s = scales[si];
  float q = rintf(W[idx] / s);
  q = fminf(fmaxf(q, -127.f), 127.f);
  WT[(size_t)c * rows + r] = (signed char)q;
}

// ---------------------------------------------------------------------------
// Quantize to bf16 integers (exact, <=7 mantissa bits).
// ---------------------------------------------------------------------------
__global__ void quant_bf_k(const float* __restrict__ W, const float* __restrict__ scales,
                           int si, ushort* __restrict__ out, int n) {
  int idx = blockIdx.x * 256 + threadIdx.x;
  if (idx >= n) return;
  float s = scales[si];
  float q = rintf(W[idx] / s);
  q = fminf(fmaxf(q, -127.f), 127.f);
  out[idx] = (ushort)(__float_as_uint(q) >> 16);
}

// ---------------------------------------------------------------------------
// Phase A: cur1[t,b,h] = sum_i data[b,i,t] * W1qT[i,h].  fp32, 128x128 tile,
// BK=16, double-buffered LDS with global_load_lds (direct-to-LDS DMA, no VGPR
// round-trip).  FMA order UNCHANGED from rounds 1-3 (ascending k, single
// accumulator per output) -> bit-identical cur1.
// ---------------------------------------------------------------------------
__global__ __launch_bounds__(256) void gemm_cur1_k(const float* __restrict__ data,
                                                   const float* __restrict__ W1qT,
                                                   float* __restrict__ cur1) {
  const int b  = blockIdx.y;
  const int t0 = (blockIdx.x >> 2) << 7;
  const int h0 = (blockIdx.x & 3) << 7;
  const int tid = threadIdx.x;

  __shared__ float As[2][16][128];   // 16 KB each buf (A+B): 32 KB total
  __shared__ float Bs[2][16][128];

  const int ty = tid >> 4, tx = tid & 15;
  const int wv = tid >> 6;        // wave id 0..3
  const int ln = tid & 63;
  const int lrow = ln >> 5;       // 0..1 (row within a 1KB wave-load)
  const int lcol = ln & 31;       // 16B column

  float acc[8][8];
#pragma unroll
  for (int i = 0; i < 8; i++)
#pragma unroll
    for (int j = 0; j < 8; j++) acc[i][j] = 0.f;

  const float* dbase = data + (size_t)b * NIN_ * T_;

  // wave wv stages rows [4*wv, 4*wv+4) of each 16-row panel: 2 wave-loads per
  // matrix (each load = 64 lanes x 16B = 2 rows of 512B).  LDS dest is
  // wave-uniform base + lane*16 -> rows must be contiguous 512B (they are).
  auto issue = [&](int kb, int buf) {
#pragma unroll
    for (int j = 0; j < 2; j++) {
      const int kr = (wv << 2) + (j << 1);
      const float* ga = dbase + (size_t)(kb + kr + lrow) * T_ + t0 + (lcol << 2);
      __builtin_amdgcn_global_load_lds((gl_cu)ga, (ls_u)&As[buf][kr][0], 16, 0, 0);
      const float* gb = W1qT + (size_t)(kb + kr + lrow) * H1_ + h0 + (lcol << 2);
      __builtin_amdgcn_global_load_lds((gl_cu)gb, (ls_u)&Bs[buf][kr][0], 16, 0, 0);
    }
  };

  issue(0, 0);

  for (int p = 0; p < 32; p++) {
    const int cur = p & 1;
    __syncthreads();                 // drains vmcnt -> buf[cur] ready; prev compute done
    if (p < 31) issue((p + 1) << 4, cur ^ 1);
#pragma unroll
    for (int k = 0; k < 16; k++) {
      float4 A0 = *(const float4*)&As[cur][k][ty * 4];
      float4 A1 = *(const float4*)&As[cur][k][64 + ty * 4];
      float4 B0 = *(const float4*)&Bs[cur][k][tx * 4];
      float4 B1 = *(const float4*)&Bs[cur][k][64 + tx * 4];
      float a[8] = {A0.x, A0.y, A0.z, A0.w, A1.x, A1.y, A1.z, A1.w};
      float w[8] = {B0.x, B0.y, B0.z, B0.w, B1.x, B1.y, B1.z, B1.w};
#pragma unroll
      for (int i = 0; i < 8; i++)
#pragma unroll
        for (int j = 0; j < 8; j++)
          acc[i][j] = fmaf(a[i], w[j], acc[i][j]);
    }
  }

#pragma unroll
  for (int i = 0; i < 8; i++) {
    int row = (i < 4) ? (ty * 4 + i) : (64 + ty * 4 + (i - 4));
    float* op = cur1 + (size_t)(t0 + row) * (B_ * H1_) + (size_t)b * H1_ + h0;
    float4 cA = {acc[i][0], acc[i][1], acc[i][2], acc[i][3]};
    float4 cB = {acc[i][4], acc[i][5], acc[i][6], acc[i][7]};
    *(float4*)(op + tx * 4)      = cA;
    *(float4*)(op + 64 + tx * 4) = cB;
  }
}

// ---------------------------------------------------------------------------
// scan1: parallel per-neuron layer-1 LIF scan (op order unchanged).
// ---------------------------------------------------------------------------
__global__ __launch_bounds__(256) void scan1_k(const float* __restrict__ cur1,
                                               unsigned char* __restrict__ s1u,
                                               const float* __restrict__ beta1p,
                                               const float* __restrict__ th1p) {
  const int n = blockIdx.x * 256 + threadIdx.x;
  const float b1 = fminf(fmaxf(beta1p[0], 0.f), 1.f);
  const float th1 = th1p[0];
  const size_t S = (size_t)B_ * H1_;
  float m1 = 0.f;
  for (int t = 0; t < T_; t += 4) {
    float c0 = cur1[(size_t)t * S + n];
    float c1 = cur1[(size_t)(t + 1) * S + n];
    float c2 = cur1[(size_t)(t + 2) * S + n];
    float c3 = cur1[(size_t)(t + 3) * S + n];
    m1 = b1 * m1 + c0; bool s0 = m1 - th1 > 0.f; if (s0) m1 = 0.f;
    s1u[(size_t)t * S + n] = s0;
    m1 = b1 * m1 + c1; bool s1 = m1 - th1 > 0.f; if (s1) m1 = 0.f;
    s1u[(size_t)(t + 1) * S + n] = s1;
    m1 = b1 * m1 + c2; bool s2 = m1 - th1 > 0.f; if (s2) m1 = 0.f;
    s1u[(size_t)(t + 2) * S + n] = s2;
    m1 = b1 * m1 + c3; bool s3 = m1 - th1 > 0.f; if (s3) m1 = 0.f;
    s1u[(size_t)(t + 3) * S + n] = s3;
  }
}

// ---------------------------------------------------------------------------
// Spike GEMM via bf16 MFMA (exact integer sums).
// ---------------------------------------------------------------------------
__global__ __launch_bounds__(256) void gemm_spk_k(const unsigned char* __restrict__ A8,
                                                  const ushort* __restrict__ Bw,
                                                  float* __restrict__ C, int N) {
  __shared__ short As[128 * 72];
  __shared__ short Bs[128 * 72];
  const int tid = threadIdx.x;
  const int m0 = blockIdx.y << 7;
  const int n0 = blockIdx.x << 7;
  const int lane = tid & 63, wave = tid >> 6;
  const int quad = lane >> 4, lm = lane & 15;
  const int wm = wave << 5;

  f32x4 acc[2][8];
#pragma unroll
  for (int s = 0; s < 2; s++)
#pragma unroll
    for (int n = 0; n < 8; n++) acc[s][n] = (f32x4){0.f, 0.f, 0.f, 0.f};

  for (int kb = 0; kb < 512; kb += 64) {
    uint4 av[2], bv[4];
#pragma unroll
    for (int i = 0; i < 2; i++) {
      int ch = tid + (i << 8);
      int row = ch >> 2, offB = (ch & 3) << 4;
      av[i] = *(const uint4*)(A8 + (size_t)(m0 + row) * 512 + kb + offB);
    }
#pragma unroll
    for (int i = 0; i < 4; i++) {
      int ch = tid + (i << 8);
      int row = ch >> 3, off = (ch & 7) << 3;
      bv[i] = *(const uint4*)(Bw + (size_t)(n0 + row) * 512 + kb + off);
    }
    __syncthreads();
#pragma unroll
    for (int i = 0; i < 2; i++) {
      int ch = tid + (i << 8);
      int row = ch >> 2, offB = (ch & 3) << 4;
      unsigned u[4] = {av[i].x, av[i].y, av[i].z, av[i].w};
      unsigned d[8];
#pragma unroll
      for (int w = 0; w < 4; w++) {
        unsigned uu = u[w];
        d[2 * w]     = ((uu & 1u) | ((uu & 0x100u) << 8)) * 0x3F80u;
        d[2 * w + 1] = (((uu >> 16) & 1u) | ((uu & 0x1000000u) >> 8)) * 0x3F80u;
      }
      uint4* dst = (uint4*)&As[row * 72 + offB];
      dst[0] = make_uint4(d[0], d[1], d[2], d[3]);
      dst[1] = make_uint4(d[4], d[5], d[6], d[7]);
    }
#pragma unroll
    for (int i = 0; i < 4; i++) {
      int ch = tid + (i << 8);
      int row = ch >> 3, off = (ch & 7) << 3;
      *(uint4*)&Bs[row * 72 + off] = bv[i];
    }
    __syncthreads();
#pragma unroll
    for (int kc = 0; kc < 64; kc += 32) {
      bf16x8 af0 = *(const bf16x8*)&As[(wm + lm) * 72 + kc + quad * 8];
      bf16x8 af1 = *(const bf16x8*)&As[(wm + 16 + lm) * 72 + kc + quad * 8];
      bf16x8 bfr[8];
#pragma unroll
      for (int n = 0; n < 8; n++)
        bfr[n] = *(const bf16x8*)&Bs[((n << 4) + lm) * 72 + kc + quad * 8];
#pragma unroll
      for (int n = 0; n < 8; n++) {
        acc[0][n] = __builtin_amdgcn_mfma_f32_16x16x32_bf16(af0, bfr[n], acc[0][n], 0, 0, 0);
        acc[1][n] = __builtin_amdgcn_mfma_f32_16x16x32_bf16(af1, bfr[n], acc[1][n], 0, 0, 0);
      }
    }
    __syncthreads();
  }

#pragma unroll
  for (int s = 0; s < 2; s++)
#pragma unroll
    for (int n = 0; n < 8; n++) {
      int row = m0 + wm + (s << 4) + quad * 4;
      int col = n0 + (n << 4) + lm;
#pragma unroll
      for (int r = 0; r < 4; r++)
        C[(size_t)(row + r) * N + col] = acc[s][n][r];
    }
}

// ---------------------------------------------------------------------------
__device__ __forceinline__ void unp_add(unsigned w, int* a) {
  int iw = (int)w;
  a[0] += (iw << 24) >> 24;
  a[1] += (iw << 16) >> 24;
  a[2] += (iw << 8) >> 24;
  a[3] += iw >> 24;
}

// ---------------------------------------------------------------------------
// Sequential recurrent layer.  One block per batch row, 1024 threads.
// Spike-list build via ballot (1 atomic per wave) — list order changes but the
// gather is an order-independent exact integer sum -> h bit-identical.
// ---------------------------------------------------------------------------
__global__ __launch_bounds__(1024) void recurrent_k(
    const float* __restrict__ cur2a,
    const signed char* __restrict__ WrT,
    unsigned char* __restrict__ sru,
    const float* __restrict__ scales,
    const float* __restrict__ betarp, const float* __restrict__ thrp) {
  const int b = blockIdx.x;
  const int tid = threadIdx.x;
  const float s2sc = scales[1];
  const float srsc = scales[2];
  const float br = fminf(fmaxf(betarp[0], 0.f), 1.f);
  const float thr = thrp[0];

  const unsigned* WrT4 = (const unsigned*)WrT;

  __shared__ int red[8][H2_];
  __shared__ int lst[2][H2_];
  __shared__ int nc[2];

  if (tid < 2) nc[tid] = 0;
  __syncthreads();

  float mr = 0.f, sr_own = 0.f;
  const int g = tid >> 7;
  const int c = tid & 127;

  for (int t = 0; t < T_; t++) {
    const int old = t & 1, nxt = old ^ 1;
    float c2 = 0.f;
    if (tid < H2_) c2 = cur2a[((size_t)t * B_ + b) * H2_ + tid];
    if (tid == 1023) nc[nxt] = 0;
    const int n = nc[old];
    const int* L = lst[old];

    int a4[4] = {0, 0, 0, 0};
    int k = g;
    for (; k + 56 < n; k += 64) {
      int i0 = L[k],      i1 = L[k + 8],  i2 = L[k + 16], i3 = L[k + 24];
      int i4 = L[k + 32], i5 = L[k + 40], i6 = L[k + 48], i7 = L[k + 56];
      unsigned w0 = WrT4[(i0 << 7) + c], w1 = WrT4[(i1 << 7) + c];
      unsigned w2 = WrT4[(i2 << 7) + c], w3 = WrT4[(i3 << 7) + c];
      unsigned w4 = WrT4[(i4 << 7) + c], w5 = WrT4[(i5 << 7) + c];
      unsigned w6 = WrT4[(i6 << 7) + c], w7 = WrT4[(i7 << 7) + c];
      unp_add(w0, a4); unp_add(w1, a4); unp_add(w2, a4); unp_add(w3, a4);
      unp_add(w4, a4); unp_add(w5, a4); unp_add(w6, a4); unp_add(w7, a4);
    }
    for (; k + 24 < n; k += 32) {
      int i0 = L[k], i1 = L[k + 8], i2 = L[k + 16], i3 = L[k + 24];
      unsigned w0 = WrT4[(i0 << 7) + c], w1 = WrT4[(i1 << 7) + c];
      unsigned w2 = WrT4[(i2 << 7) + c], w3 = WrT4[(i3 << 7) + c];
      unp_add(w0, a4); unp_add(w1, a4); unp_add(w2, a4); unp_add(w3, a4);
    }
    for (; k < n; k += 8) unp_add(WrT4[(L[k] << 7) + c], a4);
    *(int4*)&red[g][c << 2] = make_int4(a4[0], a4[1], a4[2], a4[3]);
    __syncthreads();                               // S1

    bool spike = false;
    if (tid < H2_) {
      int acc = red[0][tid] + red[1][tid] + red[2][tid] + red[3][tid]
              + red[4][tid] + red[5][tid] + red[6][tid] + red[7][tid];
      float h = s2sc * c2 + srsc * (float)acc;
      mr = (br * mr + h) * (1.f - sr_own);
      sr_own = (mr - thr > 0.f) ? 1.f : 0.f;
      sru[((size_t)t * B_ + b) * H2_ + tid] = (unsigned char)(sr_own != 0.f);
      spike = (sr_own != 0.f);
    }
    unsigned long long bm = __ballot(spike);
    if (bm != 0ull) {
      const int lane = tid & 63;
      const int ldr = (int)__ffsll((long long)bm) - 1;
      int base = 0;
      if (lane == ldr) base = atomicAdd(&nc[nxt], (int)__popcll(bm));
      base = __shfl(base, ldr);
      if (spike)
        lst[nxt][base + (int)__popcll(bm & ((1ull << lane) - 1ull))] = tid;
    }
    __syncthreads();                               // S2
  }
}

// ---------------------------------------------------------------------------
// scan3: parallel layer-2 LIF scan over precomputed cur3 sums.
// ---------------------------------------------------------------------------
__global__ __launch_bounds__(256) void scan3_k(const float* __restrict__ cur3,
                                               float* __restrict__ out,
                                               const float* __restrict__ scales,
                                               const float* __restrict__ beta2p,
                                               const float* __restrict__ th2p) {
  const int n = blockIdx.x * 256 + threadIdx.x;
  const float s3sc = scales[3];
  const float b2 = fminf(fmaxf(beta2p[0], 0.f), 1.f);
  const float th2 = th2p[0];
  const size_t S = (size_t)B_ * OUT_;
  float m2 = 0.f;
  for (int t = 0; t < T_; t += 4) {
    float v0 = cur3[(size_t)t * S + n];
    float v1 = cur3[(size_t)(t + 1) * S + n];
    float v2 = cur3[(size_t)(t + 2) * S + n];
    float v3 = cur3[(size_t)(t + 3) * S + n];
    m2 = b2 * m2 + s3sc * v0; float p0 = (m2 - th2 > 0.f) ? 1.f : 0.f; m2 *= (1.f - p0);
    out[(size_t)t * S + n] = p0;
    m2 = b2 * m2 + s3sc * v1; float p1 = (m2 - th2 > 0.f) ? 1.f : 0.f; m2 *= (1.f - p1);
    out[(size_t)(t + 1) * S + n] = p1;
    m2 = b2 * m2 + s3sc * v2; float p2 = (m2 - th2 > 0.f) ? 1.f : 0.f; m2 *= (1.f - p2);
    out[(size_t)(t + 2) * S + n] = p2;
    m2 = b2 * m2 + s3sc * v3; float p3 = (m2 - th2 > 0.f) ? 1.f : 0.f; m2 *= (1.f - p3);
    out[(size_t)(t + 3) * S + n] = p3;
  }
}

// ---------------------------------------------------------------------------
extern "C" void kernel_launch(void* const* d_in, const int* in_sizes, int n_in,
                              void* d_out, int out_size, void* d_ws, size_t ws_size,
                              hipStream_t stream) {
  const float* data  = (const float*)d_in[0];
  const float* W1    = (const float*)d_in[1];
  const float* W2    = (const float*)d_in[2];
  const float* Wr    = (const float*)d_in[3];
  const float* W3    = (const float*)d_in[4];
  const float* beta1 = (const float*)d_in[5];
  const float* th1   = (const float*)d_in[6];
  const float* betar = (const float*)d_in[7];
  const float* thr   = (const float*)d_in[8];
  const float* beta2 = (const float*)d_in[9];
  const float* th2   = (const float*)d_in[10];

  char* ws = (char*)d_ws;
  float*         scales = (float*)ws;                                   // @0
  float*         W1qT   = (float*)(ws + 4096);                          // 1 MB [NIN][H1]
  ushort*        W2bf   = (ushort*)(ws + 4096 + 1048576);               // 512 KB [H2][H1]
  ushort*        W3bf   = (ushort*)(ws + 4096 + 1048576 + 524288);      // 128 KB [OUT][H2]
  signed char*   WrT    = (signed char*)(ws + 4096 + 1048576 + 524288 + 131072); // 256 KB
  // region A (128 MB): cur1 -> cur2a -> cur3 (sequential lifetimes)
  float*         regA   = (float*)(ws + (size_t)4194304);
  // region B (64 MB): s1u + sru
  unsigned char* regB   = (unsigned char*)(ws + (size_t)4194304 + 134217728);

  float* cur1  = regA;
  float* cur2a = regA;
  float* cur3  = regA;
  unsigned char* s1u = regB;
  unsigned char* sru = regB + (size_t)33554432;

  hipLaunchKernelGGL(absmax_k, dim3(4), dim3(256), 0, stream, W1, W2, Wr, W3, scales);
  hipLaunchKernelGGL(quant_w1t_k, dim3((H1_ * NIN_) / 256), dim3(256), 0, stream, W1, scales, W1qT);
  hipLaunchKernelGGL(quant_bf_k, dim3((H2_ * H1_) / 256), dim3(256), 0, stream, W2, scales, 1, W2bf, H2_ * H1_);
  hipLaunchKernelGGL(quant_t_k, dim3((H2_ * H2_) / 256), dim3(256), 0, stream, Wr, scales, 2, WrT, H2_, H2_);
  hipLaunchKernelGGL(quant_bf_k, dim3((OUT_ * H2_) / 256), dim3(256), 0, stream, W3, scales, 3, W3bf, OUT_ * H2_);

  hipLaunchKernelGGL(gemm_cur1_k, dim3(8, 256), dim3(256), 0, stream, data, W1qT, cur1);
  hipLaunchKernelGGL(scan1_k, dim3((B_ * H1_) / 256), dim3(256), 0, stream, cur1, s1u, beta1, th1);
  hipLaunchKernelGGL(gemm_spk_k, dim3(4, 512), dim3(256), 0, stream, s1u, W2bf, cur2a, H2_);
  hipLaunchKernelGGL(recurrent_k, dim3(256), dim3(1024), 0, stream, cur2a, WrT, sru, scales, betar, thr);
  hipLaunchKernelGGL(gemm_spk_k, dim3(1, 512), dim3(256), 0, stream, sru, W3bf, cur3, OUT_);
  hipLaunchKernelGGL(scan3_k, dim3((B_ * OUT_) / 256), dim3(256), 0, stream, cur3, (float*)d_out, scales, beta2, th2);
}

// Round 7
// 1030.273 us; speedup vs baseline: 1.5570x; 1.0276x over previous
//
#include <hip/hip_runtime.h>

#define B_   256
#define NIN_ 512
#define T_   256
#define H1_  512
#define H2_  512
#define OUT_ 128

typedef __attribute__((ext_vector_type(8))) short bf16x8;
typedef __attribute__((ext_vector_type(4))) float f32x4;
typedef __attribute__((address_space(1))) const unsigned int* gl_cu;
typedef __attribute__((address_space(3))) unsigned int* ls_u;

// ---------------------------------------------------------------------------
// Per-tensor absmax -> scale = max|W|/127.  One block per tensor.
// ---------------------------------------------------------------------------
__global__ void absmax_k(const float* __restrict__ W1, const float* __restrict__ W2,
                         const float* __restrict__ Wr, const float* __restrict__ W3,
                         float* __restrict__ scales) {
  const float* W; int n;
  switch (blockIdx.x) {
    case 0:  W = W1; n = H1_ * NIN_; break;
    case 1:  W = W2; n = H2_ * H1_;  break;
    case 2:  W = Wr; n = H2_ * H2_;  break;
    default: W = W3; n = OUT_ * H2_; break;
  }
  int tid = threadIdx.x;
  float m = 0.f;
  const float4* W4 = (const float4*)W;
  int n4 = n >> 2;
  for (int i = tid; i < n4; i += 256) {
    float4 v = W4[i];
    m = fmaxf(m, fmaxf(fmaxf(fabsf(v.x), fabsf(v.y)), fmaxf(fabsf(v.z), fabsf(v.w))));
  }
  __shared__ float red[256];
  red[tid] = m;
  __syncthreads();
  for (int s = 128; s > 0; s >>= 1) {
    if (tid < s) red[tid] = fmaxf(red[tid], red[tid + s]);
    __syncthreads();
  }
  if (tid == 0) scales[blockIdx.x] = red[0] / 127.0f;
}

// ---------------------------------------------------------------------------
// Fused quantization of all four weight tensors (one launch).
//  blocks 0..1023    : W1 -> fp32 q*s, transposed [NIN][H1]    (W1qT)
//  blocks 1024..2047 : W2 -> bf16 int q, row-major [H2][H1]    (W2bf)
//  blocks 2048..3071 : Wr -> int8 q, presyn-major [H2][H2]     (WrT, transposed)
//  blocks 3072..3327 : W3 -> bf16 int q, row-major [OUT][H2]   (W3bf)
// Values identical to round-5's separate kernels.
// ---------------------------------------------------------------------------
__global__ void quant_all_k(const float* __restrict__ W1, const float* __restrict__ W2,
                            const float* __restrict__ Wr, const float* __restrict__ W3,
                            const float* __restrict__ scales,
                            float* __restrict__ W1qT, ushort* __restrict__ W2bf,
                            signed char* __restrict__ WrT, ushort* __restrict__ W3bf) {
  const int blk = blockIdx.x;
  if (blk < 1024) {
    int idx = blk * 256 + threadIdx.x;
    int h = idx & (H1_ - 1), i = idx >> 9;
    float s = scales[0];
    float q = rintf(W1[h * NIN_ + i] / s);
    q = fminf(fmaxf(q, -127.f), 127.f);
    W1qT[idx] = q * s;
  } else if (blk < 2048) {
    int idx = (blk - 1024) * 256 + threadIdx.x;
    float s = scales[1];
    float q = rintf(W2[idx] / s);
    q = fminf(fmaxf(q, -127.f), 127.f);
    W2bf[idx] = (ushort)(__float_as_uint(q) >> 16);
  } else if (blk < 3072) {
    int idx = (blk - 2048) * 256 + threadIdx.x;
    int r = idx >> 9, c = idx & (H2_ - 1);
    float s = scales[2];
    float q = rintf(Wr[idx] / s);
    q = fminf(fmaxf(q, -127.f), 127.f);
    WrT[(size_t)c * H2_ + r] = (signed char)q;
  } else {
    int idx = (blk - 3072) * 256 + threadIdx.x;
    float s = scales[3];
    float q = rintf(W3[idx] / s);
    q = fminf(fmaxf(q, -127.f), 127.f);
    W3bf[idx] = (ushort)(__float_as_uint(q) >> 16);
  }
}

// ---------------------------------------------------------------------------
// Phase A: cur1[t,b,h] = sum_i data[b,i,t] * W1qT[i,h].  fp32, 128x128 tile,
// BK=16, double-buffered LDS with global_load_lds.  FMA order UNCHANGED from
// rounds 1-5 (ascending k, single accumulator) -> bit-identical cur1.  GOLDEN.
// ---------------------------------------------------------------------------
__global__ __launch_bounds__(256) void gemm_cur1_k(const float* __restrict__ data,
                                                   const float* __restrict__ W1qT,
                                                   float* __restrict__ cur1) {
  const int b  = blockIdx.y;
  const int t0 = (blockIdx.x >> 2) << 7;
  const int h0 = (blockIdx.x & 3) << 7;
  const int tid = threadIdx.x;

  __shared__ float As[2][16][128];
  __shared__ float Bs[2][16][128];

  const int ty = tid >> 4, tx = tid & 15;
  const int wv = tid >> 6;
  const int ln = tid & 63;
  const int lrow = ln >> 5;
  const int lcol = ln & 31;

  float acc[8][8];
#pragma unroll
  for (int i = 0; i < 8; i++)
#pragma unroll
    for (int j = 0; j < 8; j++) acc[i][j] = 0.f;

  const float* dbase = data + (size_t)b * NIN_ * T_;

  auto issue = [&](int kb, int buf) {
#pragma unroll
    for (int j = 0; j < 2; j++) {
      const int kr = (wv << 2) + (j << 1);
      const float* ga = dbase + (size_t)(kb + kr + lrow) * T_ + t0 + (lcol << 2);
      __builtin_amdgcn_global_load_lds((gl_cu)ga, (ls_u)&As[buf][kr][0], 16, 0, 0);
      const float* gb = W1qT + (size_t)(kb + kr + lrow) * H1_ + h0 + (lcol << 2);
      __builtin_amdgcn_global_load_lds((gl_cu)gb, (ls_u)&Bs[buf][kr][0], 16, 0, 0);
    }
  };

  issue(0, 0);

  for (int p = 0; p < 32; p++) {
    const int cur = p & 1;
    __syncthreads();
    if (p < 31) issue((p + 1) << 4, cur ^ 1);
#pragma unroll
    for (int k = 0; k < 16; k++) {
      float4 A0 = *(const float4*)&As[cur][k][ty * 4];
      float4 A1 = *(const float4*)&As[cur][k][64 + ty * 4];
      float4 B0 = *(const float4*)&Bs[cur][k][tx * 4];
      float4 B1 = *(const float4*)&Bs[cur][k][64 + tx * 4];
      float a[8] = {A0.x, A0.y, A0.z, A0.w, A1.x, A1.y, A1.z, A1.w};
      float w[8] = {B0.x, B0.y, B0.z, B0.w, B1.x, B1.y, B1.z, B1.w};
#pragma unroll
      for (int i = 0; i < 8; i++)
#pragma unroll
        for (int j = 0; j < 8; j++)
          acc[i][j] = fmaf(a[i], w[j], acc[i][j]);
    }
  }

#pragma unroll
  for (int i = 0; i < 8; i++) {
    int row = (i < 4) ? (ty * 4 + i) : (64 + ty * 4 + (i - 4));
    float* op = cur1 + (size_t)(t0 + row) * (B_ * H1_) + (size_t)b * H1_ + h0;
    float4 cA = {acc[i][0], acc[i][1], acc[i][2], acc[i][3]};
    float4 cB = {acc[i][4], acc[i][5], acc[i][6], acc[i][7]};
    *(float4*)(op + tx * 4)      = cA;
    *(float4*)(op + 64 + tx * 4) = cB;
  }
}

// ---------------------------------------------------------------------------
// scan1: parallel per-neuron layer-1 LIF scan (op order unchanged).
// ---------------------------------------------------------------------------
__global__ __launch_bounds__(256) void scan1_k(const float* __restrict__ cur1,
                                               unsigned char* __restrict__ s1u,
                                               const float* __restrict__ beta1p,
                                               const float* __restrict__ th1p) {
  const int n = blockIdx.x * 256 + threadIdx.x;
  const float b1 = fminf(fmaxf(beta1p[0], 0.f), 1.f);
  const float th1 = th1p[0];
  const size_t S = (size_t)B_ * H1_;
  float m1 = 0.f;
  for (int t = 0; t < T_; t += 4) {
    float c0 = cur1[(size_t)t * S + n];
    float c1 = cur1[(size_t)(t + 1) * S + n];
    float c2 = cur1[(size_t)(t + 2) * S + n];
    float c3 = cur1[(size_t)(t + 3) * S + n];
    m1 = b1 * m1 + c0; bool s0 = m1 - th1 > 0.f; if (s0) m1 = 0.f;
    s1u[(size_t)t * S + n] = s0;
    m1 = b1 * m1 + c1; bool s1 = m1 - th1 > 0.f; if (s1) m1 = 0.f;
    s1u[(size_t)(t + 1) * S + n] = s1;
    m1 = b1 * m1 + c2; bool s2 = m1 - th1 > 0.f; if (s2) m1 = 0.f;
    s1u[(size_t)(t + 2) * S + n] = s2;
    m1 = b1 * m1 + c3; bool s3 = m1 - th1 > 0.f; if (s3) m1 = 0.f;
    s1u[(size_t)(t + 3) * S + n] = s3;
  }
}

// ---------------------------------------------------------------------------
// Spike GEMM via bf16 MFMA (exact integer sums).  VERIFIED.
// ---------------------------------------------------------------------------
__global__ __launch_bounds__(256) void gemm_spk_k(const unsigned char* __restrict__ A8,
                                                  const ushort* __restrict__ Bw,
                                                  float* __restrict__ C, int N) {
  __shared__ short As[128 * 72];
  __shared__ short Bs[128 * 72];
  const int tid = threadIdx.x;
  const int m0 = blockIdx.y << 7;
  const int n0 = blockIdx.x << 7;
  const int lane = tid & 63, wave = tid >> 6;
  const int quad = lane >> 4, lm = lane & 15;
  const int wm = wave << 5;

  f32x4 acc[2][8];
#pragma unroll
  for (int s = 0; s < 2; s++)
#pragma unroll
    for (int n = 0; n < 8; n++) acc[s][n] = (f32x4){0.f, 0.f, 0.f, 0.f};

  for (int kb = 0; kb < 512; kb += 64) {
    uint4 av[2], bv[4];
#pragma unroll
    for (int i = 0; i < 2; i++) {
      int ch = tid + (i << 8);
      int row = ch >> 2, offB = (ch & 3) << 4;
      av[i] = *(const uint4*)(A8 + (size_t)(m0 + row) * 512 + kb + offB);
    }
#pragma unroll
    for (int i = 0; i < 4; i++) {
      int ch = tid + (i << 8);
      int row = ch >> 3, off = (ch & 7) << 3;
      bv[i] = *(const uint4*)(Bw + (size_t)(n0 + row) * 512 + kb + off);
    }
    __syncthreads();
#pragma unroll
    for (int i = 0; i < 2; i++) {
      int ch = tid + (i << 8);
      int row = ch >> 2, offB = (ch & 3) << 4;
      unsigned u[4] = {av[i].x, av[i].y, av[i].z, av[i].w};
      unsigned d[8];
#pragma unroll
      for (int w = 0; w < 4; w++) {
        unsigned uu = u[w];
        d[2 * w]     = ((uu & 1u) | ((uu & 0x100u) << 8)) * 0x3F80u;
        d[2 * w + 1] = (((uu >> 16) & 1u) | ((uu & 0x1000000u) >> 8)) * 0x3F80u;
      }
      uint4* dst = (uint4*)&As[row * 72 + offB];
      dst[0] = make_uint4(d[0], d[1], d[2], d[3]);
      dst[1] = make_uint4(d[4], d[5], d[6], d[7]);
    }
#pragma unroll
    for (int i = 0; i < 4; i++) {
      int ch = tid + (i << 8);
      int row = ch >> 3, off = (ch & 7) << 3;
      *(uint4*)&Bs[row * 72 + off] = bv[i];
    }
    __syncthreads();
#pragma unroll
    for (int kc = 0; kc < 64; kc += 32) {
      bf16x8 af0 = *(const bf16x8*)&As[(wm + lm) * 72 + kc + quad * 8];
      bf16x8 af1 = *(const bf16x8*)&As[(wm + 16 + lm) * 72 + kc + quad * 8];
      bf16x8 bfr[8];
#pragma unroll
      for (int n = 0; n < 8; n++)
        bfr[n] = *(const bf16x8*)&Bs[((n << 4) + lm) * 72 + kc + quad * 8];
#pragma unroll
      for (int n = 0; n < 8; n++) {
        acc[0][n] = __builtin_amdgcn_mfma_f32_16x16x32_bf16(af0, bfr[n], acc[0][n], 0, 0, 0);
        acc[1][n] = __builtin_amdgcn_mfma_f32_16x16x32_bf16(af1, bfr[n], acc[1][n], 0, 0, 0);
      }
    }
    __syncthreads();
  }

#pragma unroll
  for (int s = 0; s < 2; s++)
#pragma unroll
    for (int n = 0; n < 8; n++) {
      int row = m0 + wm + (s << 4) + quad * 4;
      int col = n0 + (n << 4) + lm;
#pragma unroll
      for (int r = 0; r < 4; r++)
        C[(size_t)(row + r) * N + col] = acc[s][n][r];
    }
}

// ---------------------------------------------------------------------------
__device__ __forceinline__ void unp_add(unsigned w, int* a) {
  int iw = (int)w;
  a[0] += (iw << 24) >> 24;
  a[1] += (iw << 16) >> 24;
  a[2] += (iw << 8) >> 24;
  a[3] += iw >> 24;
}

// ---------------------------------------------------------------------------
// Sequential recurrent layer.  One block per batch row, 1024 threads.
// Round-5 arithmetic EXACTLY (same integers summed, order-independent), with
// the gather split: presyn rows 0..255 served from a 128 KB LDS copy of WrT
// (gfx950: 160 KB addressable LDS/workgroup), rows 256..511 from L2.  Spike
// list built per half at ballot time (wave-uniform split, 1 atomic/wave).
// ---------------------------------------------------------------------------
__global__ __launch_bounds__(1024) void recurrent_k(
    const float* __restrict__ cur2a,       // [T*B, H2]
    const signed char* __restrict__ WrT,   // [H2][H2] presyn-major
    unsigned char* __restrict__ sru,       // [T*B, H2]
    const float* __restrict__ scales,
    const float* __restrict__ betarp, const float* __restrict__ thrp) {
  const int b = blockIdx.x;
  const int tid = threadIdx.x;
  const float s2sc = scales[1];
  const float srsc = scales[2];
  const float br = fminf(fmaxf(betarp[0], 0.f), 1.f);
  const float thr = thrp[0];

  const unsigned* WrT4 = (const unsigned*)WrT;   // [H2][128] dwords

  __shared__ unsigned WrL[256 * 128];   // 128 KB: presyn rows 0..255
  __shared__ int red[8][H2_];           // 16 KB
  __shared__ int lstLo[2][256];         // 2 KB
  __shared__ int lstHi[2][256];         // 2 KB
  __shared__ int ncLo[2], ncHi[2];

  // preload presyn rows 0..255 (dwords 0..32767) into LDS
  {
    const uint4* src = (const uint4*)WrT4;
    uint4* dst = (uint4*)WrL;
    for (int i = tid; i < 8192; i += 1024) dst[i] = src[i];
  }
  if (tid < 2) { ncLo[tid] = 0; ncHi[tid] = 0; }
  __syncthreads();

  float mr = 0.f, sr_own = 0.f;
  const int g = tid >> 7;        // 0..7
  const int c = tid & 127;       // dword column

  for (int t = 0; t < T_; t++) {
    const int old = t & 1, nxt = old ^ 1;
    float c2 = 0.f;
    if (tid < H2_) c2 = cur2a[((size_t)t * B_ + b) * H2_ + tid];
    if (tid == 1022) ncLo[nxt] = 0;
    if (tid == 1023) ncHi[nxt] = 0;
    const int nLo = ncLo[old];
    const int nHi = ncHi[old];
    const int* LLo = lstLo[old];
    const int* LHi = lstHi[old];

    int a4[4] = {0, 0, 0, 0};
    // ---- LDS-resident half (rows < 256) ----
    {
      int k = g;
      for (; k + 56 < nLo; k += 64) {
        int i0 = LLo[k],      i1 = LLo[k + 8],  i2 = LLo[k + 16], i3 = LLo[k + 24];
        int i4 = LLo[k + 32], i5 = LLo[k + 40], i6 = LLo[k + 48], i7 = LLo[k + 56];
        unsigned w0 = WrL[(i0 << 7) + c], w1 = WrL[(i1 << 7) + c];
        unsigned w2 = WrL[(i2 << 7) + c], w3 = WrL[(i3 << 7) + c];
        unsigned w4 = WrL[(i4 << 7) + c], w5 = WrL[(i5 << 7) + c];
        unsigned w6 = WrL[(i6 << 7) + c], w7 = WrL[(i7 << 7) + c];
        unp_add(w0, a4); unp_add(w1, a4); unp_add(w2, a4); unp_add(w3, a4);
        unp_add(w4, a4); unp_add(w5, a4); unp_add(w6, a4); unp_add(w7, a4);
      }
      for (; k + 24 < nLo; k += 32) {
        int i0 = LLo[k], i1 = LLo[k + 8], i2 = LLo[k + 16], i3 = LLo[k + 24];
        unsigned w0 = WrL[(i0 << 7) + c], w1 = WrL[(i1 << 7) + c];
        unsigned w2 = WrL[(i2 << 7) + c], w3 = WrL[(i3 << 7) + c];
        unp_add(w0, a4); unp_add(w1, a4); unp_add(w2, a4); unp_add(w3, a4);
      }
      for (; k < nLo; k += 8) unp_add(WrL[(LLo[k] << 7) + c], a4);
    }
    // ---- global half (rows >= 256) ----
    {
      int k = g;
      for (; k + 56 < nHi; k += 64) {
        int i0 = LHi[k],      i1 = LHi[k + 8],  i2 = LHi[k + 16], i3 = LHi[k + 24];
        int i4 = LHi[k + 32], i5 = LHi[k + 40], i6 = LHi[k + 48], i7 = LHi[k + 56];
        unsigned w0 = WrT4[(i0 << 7) + c], w1 = WrT4[(i1 << 7) + c];
        unsigned w2 = WrT4[(i2 << 7) + c], w3 = WrT4[(i3 << 7) + c];
        unsigned w4 = WrT4[(i4 << 7) + c], w5 = WrT4[(i5 << 7) + c];
        unsigned w6 = WrT4[(i6 << 7) + c], w7 = WrT4[(i7 << 7) + c];
        unp_add(w0, a4); unp_add(w1, a4); unp_add(w2, a4); unp_add(w3, a4);
        unp_add(w4, a4); unp_add(w5, a4); unp_add(w6, a4); unp_add(w7, a4);
      }
      for (; k + 24 < nHi; k += 32) {
        int i0 = LHi[k], i1 = LHi[k + 8], i2 = LHi[k + 16], i3 = LHi[k + 24];
        unsigned w0 = WrT4[(i0 << 7) + c], w1 = WrT4[(i1 << 7) + c];
        unsigned w2 = WrT4[(i2 << 7) + c], w3 = WrT4[(i3 << 7) + c];
        unp_add(w0, a4); unp_add(w1, a4); unp_add(w2, a4); unp_add(w3, a4);
      }
      for (; k < nHi; k += 8) unp_add(WrT4[(LHi[k] << 7) + c], a4);
    }
    *(int4*)&red[g][c << 2] = make_int4(a4[0], a4[1], a4[2], a4[3]);
    __syncthreads();                               // S1

    bool spike = false;
    if (tid < H2_) {
      int acc = red[0][tid] + red[1][tid] + red[2][tid] + red[3][tid]
              + red[4][tid] + red[5][tid] + red[6][tid] + red[7][tid];
      float h = s2sc * c2 + srsc * (float)acc;
      mr = (br * mr + h) * (1.f - sr_own);
      sr_own = (mr - thr > 0.f) ? 1.f : 0.f;
      sru[((size_t)t * B_ + b) * H2_ + tid] = (unsigned char)(sr_own != 0.f);
      spike = (sr_own != 0.f);
    }
    unsigned long long bm = __ballot(spike);
    if (bm != 0ull) {
      const int lane = tid & 63;
      const int ldr = (int)__ffsll((long long)bm) - 1;
      int* cnt = (tid < 256) ? &ncLo[nxt] : &ncHi[nxt];   // wave-uniform choice
      int* dst = (tid < 256) ? lstLo[nxt] : lstHi[nxt];
      int base = 0;
      if (lane == ldr) base = atomicAdd(cnt, (int)__popcll(bm));
      base = __shfl(base, ldr);
      if (spike)
        dst[base + (int)__popcll(bm & ((1ull << lane) - 1ull))] = tid;
    }
    __syncthreads();                               // S2
  }
}

// ---------------------------------------------------------------------------
// scan3: parallel layer-2 LIF scan over precomputed cur3 sums.
// ---------------------------------------------------------------------------
__global__ __launch_bounds__(256) void scan3_k(const float* __restrict__ cur3,
                                               float* __restrict__ out,
                                               const float* __restrict__ scales,
                                               const float* __restrict__ beta2p,
                                               const float* __restrict__ th2p) {
  const int n = blockIdx.x * 256 + threadIdx.x;
  const float s3sc = scales[3];
  const float b2 = fminf(fmaxf(beta2p[0], 0.f), 1.f);
  const float th2 = th2p[0];
  const size_t S = (size_t)B_ * OUT_;
  float m2 = 0.f;
  for (int t = 0; t < T_; t += 4) {
    float v0 = cur3[(size_t)t * S + n];
    float v1 = cur3[(size_t)(t + 1) * S + n];
    float v2 = cur3[(size_t)(t + 2) * S + n];
    float v3 = cur3[(size_t)(t + 3) * S + n];
    m2 = b2 * m2 + s3sc * v0; float p0 = (m2 - th2 > 0.f) ? 1.f : 0.f; m2 *= (1.f - p0);
    out[(size_t)t * S + n] = p0;
    m2 = b2 * m2 + s3sc * v1; float p1 = (m2 - th2 > 0.f) ? 1.f : 0.f; m2 *= (1.f - p1);
    out[(size_t)(t + 1) * S + n] = p1;
    m2 = b2 * m2 + s3sc * v2; float p2 = (m2 - th2 > 0.f) ? 1.f : 0.f; m2 *= (1.f - p2);
    out[(size_t)(t + 2) * S + n] = p2;
    m2 = b2 * m2 + s3sc * v3; float p3 = (m2 - th2 > 0.f) ? 1.f : 0.f; m2 *= (1.f - p3);
    out[(size_t)(t + 3) * S + n] = p3;
  }
}

// ---------------------------------------------------------------------------
extern "C" void kernel_launch(void* const* d_in, const int* in_sizes, int n_in,
                              void* d_out, int out_size, void* d_ws, size_t ws_size,
                              hipStream_t stream) {
  const float* data  = (const float*)d_in[0];
  const float* W1    = (const float*)d_in[1];
  const float* W2    = (const float*)d_in[2];
  const float* Wr    = (const float*)d_in[3];
  const float* W3    = (const float*)d_in[4];
  const float* beta1 = (const float*)d_in[5];
  const float* th1   = (const float*)d_in[6];
  const float* betar = (const float*)d_in[7];
  const float* thr   = (const float*)d_in[8];
  const float* beta2 = (const float*)d_in[9];
  const float* th2   = (const float*)d_in[10];

  char* ws = (char*)d_ws;
  float*         scales = (float*)ws;                                   // @0
  float*         W1qT   = (float*)(ws + 4096);                          // 1 MB [NIN][H1]
  ushort*        W2bf   = (ushort*)(ws + 4096 + 1048576);               // 512 KB [H2][H1]
  ushort*        W3bf   = (ushort*)(ws + 4096 + 1048576 + 524288);      // 128 KB [OUT][H2]
  signed char*   WrT    = (signed char*)(ws + 4096 + 1048576 + 524288 + 131072); // 256 KB
  // region A (128 MB): cur1 -> cur2a -> cur3 (sequential lifetimes)
  float*         regA   = (float*)(ws + (size_t)4194304);
  // region B (64 MB): s1u + sru
  unsigned char* regB   = (unsigned char*)(ws + (size_t)4194304 + 134217728);

  float* cur1  = regA;
  float* cur2a = regA;
  float* cur3  = regA;
  unsigned char* s1u = regB;
  unsigned char* sru = regB + (size_t)33554432;

  hipLaunchKernelGGL(absmax_k, dim3(4), dim3(256), 0, stream, W1, W2, Wr, W3, scales);
  hipLaunchKernelGGL(quant_all_k, dim3(3328), dim3(256), 0, stream,
                     W1, W2, Wr, W3, scales, W1qT, W2bf, WrT, W3bf);

  hipLaunchKernelGGL(gemm_cur1_k, dim3(8, 256), dim3(256), 0, stream, data, W1qT, cur1);
  hipLaunchKernelGGL(scan1_k, dim3((B_ * H1_) / 256), dim3(256), 0, stream, cur1, s1u, beta1, th1);
  hipLaunchKernelGGL(gemm_spk_k, dim3(4, 512), dim3(256), 0, stream, s1u, W2bf, cur2a, H2_);
  hipLaunchKernelGGL(recurrent_k, dim3(256), dim3(1024), 0, stream, cur2a, WrT, sru, scales, betar, thr);
  hipLaunchKernelGGL(gemm_spk_k, dim3(1, 512), dim3(256), 0, stream, sru, W3bf, cur3, OUT_);
  hipLaunchKernelGGL(scan3_k, dim3((B_ * OUT_) / 256), dim3(256), 0, stream, cur3, (float*)d_out, scales, beta2, th2);
}